// Round 1
// baseline (1451.614 us; speedup 1.0000x reference)
//
#include <hip/hip_runtime.h>
#include <math.h>

#define DEVI static __device__ __forceinline__

typedef __attribute__((ext_vector_type(8))) short bf16x8;
typedef __attribute__((ext_vector_type(8))) unsigned short ushort8;
typedef __attribute__((ext_vector_type(4))) float f32x4;

DEVI unsigned short f32_bf16(float f) {
  unsigned int u = __float_as_uint(f);
  u += 0x7fffu + ((u >> 16) & 1u);
  return (unsigned short)(u >> 16);
}
DEVI float bf16_f32(unsigned short h) {
  return __uint_as_float(((unsigned int)h) << 16);
}

DEVI void async16(void* lds, const void* g) {
  __builtin_amdgcn_global_load_lds(
      (const __attribute__((address_space(1))) void*)g,
      (__attribute__((address_space(3))) void*)lds,
      16, 0, 0);
}

// ---------------------------------------------------------------- casts ----
__global__ __launch_bounds__(256) void cast_bf16_kernel(
    const float* __restrict__ src, unsigned short* __restrict__ dst, long n8) {
  long i = (long)blockIdx.x * 256 + threadIdx.x;
  if (i >= n8) return;
  const float4 a = *(const float4*)(src + i * 8);
  const float4 b = *(const float4*)(src + i * 8 + 4);
  ushort8 o;
  o[0] = f32_bf16(a.x); o[1] = f32_bf16(a.y); o[2] = f32_bf16(a.z); o[3] = f32_bf16(a.w);
  o[4] = f32_bf16(b.x); o[5] = f32_bf16(b.y); o[6] = f32_bf16(b.z); o[7] = f32_bf16(b.w);
  *(ushort8*)(dst + i * 8) = o;
}

// gate/up interleave: dst row 2j = gate j, row 2j+1 = up j.  [16384][2048]
__global__ __launch_bounds__(256) void cast_gu_kernel(
    const float* __restrict__ gate, const float* __restrict__ up,
    unsigned short* __restrict__ dst) {
  long i = (long)blockIdx.x * 256 + threadIdx.x;  // 8-elem groups, 4194304 total
  long row = i >> 8;          // 2048/8 = 256 groups per row
  long col = (i & 255) * 8;
  const float* src = ((row & 1) ? up : gate) + ((row >> 1) << 11) + col;
  const float4 a = *(const float4*)(src);
  const float4 b = *(const float4*)(src + 4);
  ushort8 o;
  o[0] = f32_bf16(a.x); o[1] = f32_bf16(a.y); o[2] = f32_bf16(a.z); o[3] = f32_bf16(a.w);
  o[4] = f32_bf16(b.x); o[5] = f32_bf16(b.y); o[6] = f32_bf16(b.z); o[7] = f32_bf16(b.w);
  *(ushort8*)(dst + i * 8) = o;
}

// ----------------------------------------------------------------- rope ----
__global__ __launch_bounds__(256) void rope_table_kernel(float2* __restrict__ tab) {
  int idx = blockIdx.x * 256 + threadIdx.x;  // < 4096*64
  int t = idx >> 6, i = idx & 63;
  // inv_freq = base^(-2i/128); ln(500000) = 13.122363377404328
  float inv = __expf(-(float)(2 * i) * (1.0f / 128.0f) * 13.122363377404328f);
  float f = (float)t * inv;
  tab[idx] = make_float2(cosf(f), sinf(f));
}

__global__ __launch_bounds__(256) void rope_apply_kernel(
    unsigned short* __restrict__ qkv, const float2* __restrict__ tab) {
  const int row = blockIdx.x;
  const int tid = threadIdx.x;
#pragma unroll
  for (int it = 0; it < 5; ++it) {
    int p = tid + it * 256;  // 0..1279 : 1024 q-pairs + 256 k-pairs
    int head = p >> 6, i = p & 63;
    int col = (p < 1024) ? (head * 128 + 2 * i) : (2048 + (head - 16) * 128 + 2 * i);
    unsigned short* ptr = qkv + (long)row * 3072 + col;
    float a = bf16_f32(ptr[0]), b = bf16_f32(ptr[1]);
    float2 cs = tab[row * 64 + i];
    float a2 = a * cs.x - b * cs.y;
    float b2 = a * cs.y + b * cs.x;
    ptr[0] = f32_bf16(a2);
    ptr[1] = f32_bf16(b2);
  }
}

// -------------------------------------------------------------- rmsnorm ----
__global__ __launch_bounds__(256) void rmsnorm_kernel(
    const float* __restrict__ x, const float* __restrict__ wgt,
    unsigned short* __restrict__ out) {
  __shared__ float red[4];
  const int row = blockIdx.x;
  const int tid = threadIdx.x;
  const float* xr = x + (long)row * 2048 + tid * 8;
  const float4 v0 = *(const float4*)(xr);
  const float4 v1 = *(const float4*)(xr + 4);
  float ss = v0.x * v0.x + v0.y * v0.y + v0.z * v0.z + v0.w * v0.w +
             v1.x * v1.x + v1.y * v1.y + v1.z * v1.z + v1.w * v1.w;
#pragma unroll
  for (int off = 1; off < 64; off <<= 1) ss += __shfl_xor(ss, off);
  if ((tid & 63) == 0) red[tid >> 6] = ss;
  __syncthreads();
  float tot = red[0] + red[1] + red[2] + red[3];
  float sc = rsqrtf(tot * (1.0f / 2048.0f) + 1e-5f);
  const float4 w0 = *(const float4*)(wgt + tid * 8);
  const float4 w1 = *(const float4*)(wgt + tid * 8 + 4);
  ushort8 o;
  o[0] = f32_bf16(v0.x * sc * w0.x); o[1] = f32_bf16(v0.y * sc * w0.y);
  o[2] = f32_bf16(v0.z * sc * w0.z); o[3] = f32_bf16(v0.w * sc * w0.w);
  o[4] = f32_bf16(v1.x * sc * w1.x); o[5] = f32_bf16(v1.y * sc * w1.y);
  o[6] = f32_bf16(v1.z * sc * w1.z); o[7] = f32_bf16(v1.w * sc * w1.w);
  *(ushort8*)(out + (long)row * 2048 + tid * 8) = o;
}

// ----------------------------------------------------------------- gemm ----
// C[M,N] = A[M,K] @ B[N,K]^T, bf16 in, f32 acc. 128x128 tile, BK=64, 4 waves.
// EPI 0: store bf16. EPI 1: store f32 = res + acc. EPI 2: swiglu on
// interleaved gate/up columns -> bf16 [M, N/2].
template <int EPI>
__global__ __launch_bounds__(256) void gemm_bt(
    const unsigned short* __restrict__ A, const unsigned short* __restrict__ B,
    void* __restrict__ Cout, const float* __restrict__ res, int M, int N, int K) {
  __shared__ __align__(16) unsigned short As[128 * 64];
  __shared__ __align__(16) unsigned short Bs[128 * 64];
  const int tid = threadIdx.x;
  const int lane = tid & 63;
  const int w = tid >> 6;
  const int c = lane & 15, g = lane >> 4;
  const long m0 = (long)blockIdx.x * 128;
  const long n0 = (long)blockIdx.y * 128;
  const int wm = (w >> 1) * 64, wn = (w & 1) * 64;

  const f32x4 fzero = {0.f, 0.f, 0.f, 0.f};
  f32x4 acc[4][4];
#pragma unroll
  for (int i = 0; i < 4; ++i)
#pragma unroll
    for (int j = 0; j < 4; ++j) acc[i][j] = fzero;

  const int srow = w * 32 + (lane >> 3);
  const int scol = (lane & 7) * 8;
  const unsigned short* Ag = A + (m0 + srow) * (long)K + scol;
  const unsigned short* Bg = B + (n0 + srow) * (long)K + scol;

  for (int k0 = 0; k0 < K; k0 += 64) {
    __syncthreads();
#pragma unroll
    for (int i = 0; i < 4; ++i) {
      async16(As + (w * 32 + i * 8) * 64, Ag + (long)i * 8 * K + k0);
      async16(Bs + (w * 32 + i * 8) * 64, Bg + (long)i * 8 * K + k0);
    }
    __syncthreads();
#pragma unroll
    for (int kk = 0; kk < 2; ++kk) {
      bf16x8 af[4], bfr[4];
#pragma unroll
      for (int tt = 0; tt < 4; ++tt) {
        af[tt] = *(const bf16x8*)(As + (wm + tt * 16 + c) * 64 + kk * 32 + g * 8);
        bfr[tt] = *(const bf16x8*)(Bs + (wn + tt * 16 + c) * 64 + kk * 32 + g * 8);
      }
#pragma unroll
      for (int i = 0; i < 4; ++i)
#pragma unroll
        for (int j = 0; j < 4; ++j)
          acc[i][j] = __builtin_amdgcn_mfma_f32_16x16x32_bf16(af[i], bfr[j], acc[i][j], 0, 0, 0);
    }
  }

#pragma unroll
  for (int i = 0; i < 4; ++i) {
#pragma unroll
    for (int j = 0; j < 4; ++j) {
      const long row0 = m0 + wm + i * 16 + g * 4;
      const long col = n0 + wn + j * 16 + c;
#pragma unroll
      for (int r = 0; r < 4; ++r) {
        float v = acc[i][j][r];
        if (EPI == 0) {
          ((unsigned short*)Cout)[(row0 + r) * N + col] = f32_bf16(v);
        } else if (EPI == 1) {
          ((float*)Cout)[(row0 + r) * N + col] = res[(row0 + r) * N + col] + v;
        } else {
          float other = __shfl_xor(v, 1);
          if (!(c & 1)) {
            float sg = v / (1.0f + __expf(-v));
            ((unsigned short*)Cout)[(row0 + r) * (long)(N >> 1) + (col >> 1)] =
                f32_bf16(sg * other);
          }
        }
      }
    }
  }
}

// ----------------------------------------------------------- v transpose ----
// v region of qkv [T, 3072] cols 2560..3071  ->  vT [512][4096]
__global__ __launch_bounds__(256) void transpose_v(
    const unsigned short* __restrict__ qkv, unsigned short* __restrict__ vT) {
  __shared__ __align__(16) unsigned short tile[64][72];
  const int tx = blockIdx.x;  // 0..63 (t blocks)
  const int dx = blockIdx.y;  // 0..7  (d blocks)
  const int tid = threadIdx.x;
  const int r = tid >> 3, cg = tid & 7;
#pragma unroll
  for (int it = 0; it < 2; ++it) {
    const unsigned short* src =
        qkv + (long)(tx * 64 + r + it * 32) * 3072 + 2560 + dx * 64 + cg * 8;
    *(ushort8*)(&tile[r + it * 32][cg * 8]) = *(const ushort8*)src;
  }
  __syncthreads();
#pragma unroll
  for (int it = 0; it < 2; ++it) {
    int d = r + it * 32;
    ushort8 v;
#pragma unroll
    for (int j = 0; j < 8; ++j) v[j] = tile[cg * 8 + j][d];
    *(ushort8*)(vT + (long)(dx * 64 + d) * 4096 + tx * 64 + cg * 8) = v;
  }
}

// ------------------------------------------------------------- attention ----
// Causal GQA flash attention. Q from qkv cols [h*128], K from cols
// [2048 + (h>>2)*128], V from vT. Block: 128 q rows (4 waves x 32), KV
// tiles of 64. Output y [T, 2048] bf16.
__global__ __launch_bounds__(256) void attn_kernel(
    const unsigned short* __restrict__ qkv, const unsigned short* __restrict__ vT,
    unsigned short* __restrict__ y) {
  constexpr int LDQ = 3072;
  constexpr float SCL = 0.08838834764831845f * 1.4426950408889634f;  // 1/sqrt(128)*log2e
  __shared__ __align__(16) unsigned short Ks[64][136];
  __shared__ __align__(16) unsigned short Vs[128][72];
  __shared__ __align__(16) unsigned short Ps[4][32][72];

  const int tid = threadIdx.x;
  const int lane = tid & 63;
  const int w = tid >> 6;
  const int c = lane & 15, g = lane >> 4;
  const int qblk = 31 - (int)blockIdx.x;  // big blocks launch first
  const int h = blockIdx.y;
  const int kvh = h >> 2;
  const int q0 = qblk * 128 + w * 32;

  const f32x4 fzero = {0.f, 0.f, 0.f, 0.f};

  // Q fragments (stay in regs for whole kernel)
  bf16x8 qf[2][4];
#pragma unroll
  for (int mt = 0; mt < 2; ++mt)
#pragma unroll
    for (int kk = 0; kk < 4; ++kk)
      qf[mt][kk] = *(const bf16x8*)(qkv + (long)(q0 + mt * 16 + c) * LDQ + h * 128 +
                                    kk * 32 + g * 8);

  f32x4 o[2][8];
#pragma unroll
  for (int mt = 0; mt < 2; ++mt)
#pragma unroll
    for (int dt = 0; dt < 8; ++dt) o[mt][dt] = fzero;
  float m[2][4], l[2][4];
#pragma unroll
  for (int mt = 0; mt < 2; ++mt)
#pragma unroll
    for (int r = 0; r < 4; ++r) { m[mt][r] = -1e30f; l[mt][r] = 0.f; }

  const int nsteps = 2 * qblk + 2;
  const int qmax_w = q0 + 31;

  for (int s = 0; s < nsteps; ++s) {
    const int kv0 = s * 64;
    __syncthreads();
    {  // stage K tile [64][128] and Vt tile [128][64]
      const int kr = tid >> 2, seg = tid & 3;
      const unsigned short* ksrc = qkv + (long)(kv0 + kr) * LDQ + 2048 + kvh * 128 + seg * 32;
#pragma unroll
      for (int i = 0; i < 4; ++i)
        *(ushort8*)(&Ks[kr][seg * 32 + i * 8]) = *(const ushort8*)(ksrc + i * 8);
      const int d = tid >> 1, hf = tid & 1;
      const unsigned short* vsrc = vT + (long)(kvh * 128 + d) * 4096 + kv0 + hf * 32;
#pragma unroll
      for (int i = 0; i < 4; ++i)
        *(ushort8*)(&Vs[d][hf * 32 + i * 8]) = *(const ushort8*)(vsrc + i * 8);
    }
    __syncthreads();
    if (kv0 > qmax_w) continue;
    const bool need_mask = (kv0 + 63 > q0);

    // S = Q K^T
    f32x4 sv[2][4];
#pragma unroll
    for (int mt = 0; mt < 2; ++mt)
#pragma unroll
      for (int nt = 0; nt < 4; ++nt) sv[mt][nt] = fzero;
#pragma unroll
    for (int kk = 0; kk < 4; ++kk) {
      bf16x8 kf[4];
#pragma unroll
      for (int nt = 0; nt < 4; ++nt)
        kf[nt] = *(const bf16x8*)(&Ks[nt * 16 + c][kk * 32 + g * 8]);
#pragma unroll
      for (int mt = 0; mt < 2; ++mt)
#pragma unroll
        for (int nt = 0; nt < 4; ++nt)
          sv[mt][nt] = __builtin_amdgcn_mfma_f32_16x16x32_bf16(qf[mt][kk], kf[nt],
                                                               sv[mt][nt], 0, 0, 0);
    }
    // scale (+ mask), exp2 domain
#pragma unroll
    for (int mt = 0; mt < 2; ++mt)
#pragma unroll
      for (int nt = 0; nt < 4; ++nt)
#pragma unroll
        for (int r = 0; r < 4; ++r) {
          float xx = sv[mt][nt][r] * SCL;
          if (need_mask) {
            int qr = q0 + mt * 16 + g * 4 + r;
            int kc = kv0 + nt * 16 + c;
            if (kc > qr) xx = -3.0e38f;
          }
          sv[mt][nt][r] = xx;
        }
    // online softmax per (mt, r)
    float al[2][4];
#pragma unroll
    for (int mt = 0; mt < 2; ++mt)
#pragma unroll
      for (int r = 0; r < 4; ++r) {
        float mx = fmaxf(fmaxf(sv[mt][0][r], sv[mt][1][r]),
                         fmaxf(sv[mt][2][r], sv[mt][3][r]));
        mx = fmaxf(mx, __shfl_xor(mx, 1));
        mx = fmaxf(mx, __shfl_xor(mx, 2));
        mx = fmaxf(mx, __shfl_xor(mx, 4));
        mx = fmaxf(mx, __shfl_xor(mx, 8));
        const float mn = fmaxf(m[mt][r], mx);
        const float a = exp2f(m[mt][r] - mn);
        m[mt][r] = mn;
        al[mt][r] = a;
        float rs = 0.f;
#pragma unroll
        for (int nt = 0; nt < 4; ++nt) {
          float p = exp2f(sv[mt][nt][r] - mn);
          sv[mt][nt][r] = p;
          rs += p;
        }
        rs += __shfl_xor(rs, 1);
        rs += __shfl_xor(rs, 2);
        rs += __shfl_xor(rs, 4);
        rs += __shfl_xor(rs, 8);
        l[mt][r] = l[mt][r] * a + rs;
      }
    // P -> LDS (bf16), rescale O
#pragma unroll
    for (int mt = 0; mt < 2; ++mt)
#pragma unroll
      for (int nt = 0; nt < 4; ++nt)
#pragma unroll
        for (int r = 0; r < 4; ++r)
          Ps[w][mt * 16 + g * 4 + r][nt * 16 + c] = f32_bf16(sv[mt][nt][r]);
#pragma unroll
    for (int mt = 0; mt < 2; ++mt)
#pragma unroll
      for (int dt = 0; dt < 8; ++dt)
#pragma unroll
        for (int r = 0; r < 4; ++r) o[mt][dt][r] *= al[mt][r];
    // PV
#pragma unroll
    for (int ks = 0; ks < 2; ++ks) {
      bf16x8 pf0 = *(const bf16x8*)(&Ps[w][c][ks * 32 + g * 8]);
      bf16x8 pf1 = *(const bf16x8*)(&Ps[w][16 + c][ks * 32 + g * 8]);
#pragma unroll
      for (int dt = 0; dt < 8; ++dt) {
        bf16x8 vf = *(const bf16x8*)(&Vs[dt * 16 + c][ks * 32 + g * 8]);
        o[0][dt] = __builtin_amdgcn_mfma_f32_16x16x32_bf16(pf0, vf, o[0][dt], 0, 0, 0);
        o[1][dt] = __builtin_amdgcn_mfma_f32_16x16x32_bf16(pf1, vf, o[1][dt], 0, 0, 0);
      }
    }
  }
  // epilogue: normalize + store
#pragma unroll
  for (int mt = 0; mt < 2; ++mt)
#pragma unroll
    for (int r = 0; r < 4; ++r) {
      const float inv = 1.0f / l[mt][r];
      const long row = q0 + mt * 16 + g * 4 + r;
#pragma unroll
      for (int dt = 0; dt < 8; ++dt)
        y[row * 2048 + h * 128 + dt * 16 + c] = f32_bf16(o[mt][dt][r] * inv);
    }
}

// ------------------------------------------------------------------ host ----
extern "C" void kernel_launch(void* const* d_in, const int* in_sizes, int n_in,
                              void* d_out, int out_size, void* d_ws, size_t ws_size,
                              hipStream_t stream) {
  (void)in_sizes; (void)n_in; (void)out_size; (void)ws_size;
  const float* x      = (const float*)d_in[0];
  // d_in[1] = attn_bias (fixed causal mask) -> handled analytically
  const float* attn_w = (const float*)d_in[2];
  const float* wq     = (const float*)d_in[3];
  const float* wk     = (const float*)d_in[4];
  const float* wv     = (const float*)d_in[5];
  const float* wo     = (const float*)d_in[6];
  const float* ffn_w  = (const float*)d_in[7];
  const float* wg     = (const float*)d_in[8];
  const float* wu     = (const float*)d_in[9];
  const float* wd     = (const float*)d_in[10];
  float* out = (float*)d_out;

  char* ws = (char*)d_ws;
  size_t off = 0;
  auto alloc = [&](size_t bytes) {
    char* p = ws + off;
    off += (bytes + 255) & ~(size_t)255;
    return p;
  };
  float2* rope_tab        = (float2*)alloc(4096UL * 64 * sizeof(float2));
  unsigned short* wqkv_b  = (unsigned short*)alloc(3072UL * 2048 * 2);
  unsigned short* wo_b    = (unsigned short*)alloc(2048UL * 2048 * 2);
  unsigned short* wgu_b   = (unsigned short*)alloc(16384UL * 2048 * 2);
  unsigned short* wd_b    = (unsigned short*)alloc(2048UL * 8192 * 2);
  unsigned short* h_b     = (unsigned short*)alloc(4096UL * 2048 * 2);  // reused as h2
  unsigned short* qkv_b   = (unsigned short*)alloc(4096UL * 3072 * 2);
  unsigned short* vT_b    = (unsigned short*)alloc(512UL * 4096 * 2);
  unsigned short* y_b     = (unsigned short*)alloc(4096UL * 2048 * 2);
  float* r1               = (float*)alloc(4096UL * 2048 * 4);
  unsigned short* t_b     = (unsigned short*)alloc(4096UL * 8192 * 2);

  // weight casts
  cast_bf16_kernel<<<2048, 256, 0, stream>>>(wq, wqkv_b, 524288);
  cast_bf16_kernel<<<512, 256, 0, stream>>>(wk, wqkv_b + 2048L * 2048, 131072);
  cast_bf16_kernel<<<512, 256, 0, stream>>>(wv, wqkv_b + 2560L * 2048, 131072);
  cast_bf16_kernel<<<2048, 256, 0, stream>>>(wo, wo_b, 524288);
  cast_gu_kernel<<<16384, 256, 0, stream>>>(wg, wu, wgu_b);
  cast_bf16_kernel<<<8192, 256, 0, stream>>>(wd, wd_b, 2097152);
  rope_table_kernel<<<1024, 256, 0, stream>>>(rope_tab);

  // attn branch
  rmsnorm_kernel<<<4096, 256, 0, stream>>>(x, attn_w, h_b);
  {
    dim3 grid(32, 24);
    gemm_bt<0><<<grid, 256, 0, stream>>>(h_b, wqkv_b, qkv_b, nullptr, 4096, 3072, 2048);
  }
  rope_apply_kernel<<<4096, 256, 0, stream>>>(qkv_b, rope_tab);
  {
    dim3 grid(64, 8);
    transpose_v<<<grid, 256, 0, stream>>>(qkv_b, vT_b);
  }
  {
    dim3 grid(32, 16);
    attn_kernel<<<grid, 256, 0, stream>>>(qkv_b, vT_b, y_b);
  }
  {
    dim3 grid(32, 16);
    gemm_bt<1><<<grid, 256, 0, stream>>>(y_b, wo_b, r1, x, 4096, 2048, 2048);
  }

  // ffn branch
  rmsnorm_kernel<<<4096, 256, 0, stream>>>(r1, ffn_w, h_b);
  {
    dim3 grid(32, 128);
    gemm_bt<2><<<grid, 256, 0, stream>>>(h_b, wgu_b, t_b, nullptr, 4096, 16384, 2048);
  }
  {
    dim3 grid(32, 16);
    gemm_bt<1><<<grid, 256, 0, stream>>>(t_b, wd_b, out, r1, 4096, 2048, 8192);
  }
}

// Round 2
// 1173.585 us; speedup vs baseline: 1.2369x; 1.2369x over previous
//
#include <hip/hip_runtime.h>
#include <math.h>

#define DEVI static __device__ __forceinline__

typedef __attribute__((ext_vector_type(8))) short bf16x8;
typedef __attribute__((ext_vector_type(4))) short bf16x4;
typedef __attribute__((ext_vector_type(8))) unsigned short ushort8;
typedef __attribute__((ext_vector_type(4))) unsigned short us4;
typedef __attribute__((ext_vector_type(4))) float f32x4;

DEVI unsigned short f32_bf16(float f) {
  unsigned int u = __float_as_uint(f);
  u += 0x7fffu + ((u >> 16) & 1u);
  return (unsigned short)(u >> 16);
}
DEVI float bf16_f32(unsigned short h) {
  return __uint_as_float(((unsigned int)h) << 16);
}

DEVI void async16(void* lds, const void* g) {
  __builtin_amdgcn_global_load_lds(
      (const __attribute__((address_space(1))) void*)g,
      (__attribute__((address_space(3))) void*)lds,
      16, 0, 0);
}

#if __has_builtin(__builtin_amdgcn_mfma_f32_16x16x16bf16_1k)
DEVI f32x4 mfma16(bf16x4 a, bf16x4 b, f32x4 c) {
  return __builtin_amdgcn_mfma_f32_16x16x16bf16_1k(a, b, c, 0, 0, 0);
}
#else
DEVI f32x4 mfma16(bf16x4 a, bf16x4 b, f32x4 c) {
  asm volatile("v_mfma_f32_16x16x16_bf16 %0, %1, %2, %0" : "+v"(c) : "v"(a), "v"(b));
  return c;
}
#endif

// ---------------------------------------------------------------- casts ----
__global__ __launch_bounds__(256) void cast_bf16_kernel(
    const float* __restrict__ src, unsigned short* __restrict__ dst, long n8) {
  long i = (long)blockIdx.x * 256 + threadIdx.x;
  if (i >= n8) return;
  const float4 a = *(const float4*)(src + i * 8);
  const float4 b = *(const float4*)(src + i * 8 + 4);
  ushort8 o;
  o[0] = f32_bf16(a.x); o[1] = f32_bf16(a.y); o[2] = f32_bf16(a.z); o[3] = f32_bf16(a.w);
  o[4] = f32_bf16(b.x); o[5] = f32_bf16(b.y); o[6] = f32_bf16(b.z); o[7] = f32_bf16(b.w);
  *(ushort8*)(dst + i * 8) = o;
}

// gate/up interleave: dst row 2j = gate j, row 2j+1 = up j.  [16384][2048]
__global__ __launch_bounds__(256) void cast_gu_kernel(
    const float* __restrict__ gate, const float* __restrict__ up,
    unsigned short* __restrict__ dst) {
  long i = (long)blockIdx.x * 256 + threadIdx.x;
  long row = i >> 8;
  long col = (i & 255) * 8;
  const float* src = ((row & 1) ? up : gate) + ((row >> 1) << 11) + col;
  const float4 a = *(const float4*)(src);
  const float4 b = *(const float4*)(src + 4);
  ushort8 o;
  o[0] = f32_bf16(a.x); o[1] = f32_bf16(a.y); o[2] = f32_bf16(a.z); o[3] = f32_bf16(a.w);
  o[4] = f32_bf16(b.x); o[5] = f32_bf16(b.y); o[6] = f32_bf16(b.z); o[7] = f32_bf16(b.w);
  *(ushort8*)(dst + i * 8) = o;
}

// ----------------------------------------------------------------- rope ----
__global__ __launch_bounds__(256) void rope_table_kernel(float2* __restrict__ tab) {
  int idx = blockIdx.x * 256 + threadIdx.x;
  int t = idx >> 6, i = idx & 63;
  float inv = __expf(-(float)(2 * i) * (1.0f / 128.0f) * 13.122363377404328f);
  float f = (float)t * inv;
  tab[idx] = make_float2(cosf(f), sinf(f));
}

__global__ __launch_bounds__(256) void rope_apply_kernel(
    unsigned short* __restrict__ qkv, const float2* __restrict__ tab) {
  const int row = blockIdx.x;
  const int tid = threadIdx.x;
#pragma unroll
  for (int it = 0; it < 5; ++it) {
    int p = tid + it * 256;
    int head = p >> 6, i = p & 63;
    int col = (p < 1024) ? (head * 128 + 2 * i) : (2048 + (head - 16) * 128 + 2 * i);
    unsigned short* ptr = qkv + (long)row * 3072 + col;
    float a = bf16_f32(ptr[0]), b = bf16_f32(ptr[1]);
    float2 cs = tab[row * 64 + i];
    float a2 = a * cs.x - b * cs.y;
    float b2 = a * cs.y + b * cs.x;
    ptr[0] = f32_bf16(a2);
    ptr[1] = f32_bf16(b2);
  }
}

// -------------------------------------------------------------- rmsnorm ----
__global__ __launch_bounds__(256) void rmsnorm_kernel(
    const float* __restrict__ x, const float* __restrict__ wgt,
    unsigned short* __restrict__ out) {
  __shared__ float red[4];
  const int row = blockIdx.x;
  const int tid = threadIdx.x;
  const float* xr = x + (long)row * 2048 + tid * 8;
  const float4 v0 = *(const float4*)(xr);
  const float4 v1 = *(const float4*)(xr + 4);
  float ss = v0.x * v0.x + v0.y * v0.y + v0.z * v0.z + v0.w * v0.w +
             v1.x * v1.x + v1.y * v1.y + v1.z * v1.z + v1.w * v1.w;
#pragma unroll
  for (int off = 1; off < 64; off <<= 1) ss += __shfl_xor(ss, off);
  if ((tid & 63) == 0) red[tid >> 6] = ss;
  __syncthreads();
  float tot = red[0] + red[1] + red[2] + red[3];
  float sc = rsqrtf(tot * (1.0f / 2048.0f) + 1e-5f);
  const float4 w0 = *(const float4*)(wgt + tid * 8);
  const float4 w1 = *(const float4*)(wgt + tid * 8 + 4);
  ushort8 o;
  o[0] = f32_bf16(v0.x * sc * w0.x); o[1] = f32_bf16(v0.y * sc * w0.y);
  o[2] = f32_bf16(v0.z * sc * w0.z); o[3] = f32_bf16(v0.w * sc * w0.w);
  o[4] = f32_bf16(v1.x * sc * w1.x); o[5] = f32_bf16(v1.y * sc * w1.y);
  o[6] = f32_bf16(v1.z * sc * w1.z); o[7] = f32_bf16(v1.w * sc * w1.w);
  *(ushort8*)(out + (long)row * 2048 + tid * 8) = o;
}

// ----------------------------------------------------------------- gemm ----
// C[M,N] = A[M,K] @ B[N,K]^T, bf16 in, f32 acc. 128x128 tile, BK=64, 4 waves.
// EPI 0: store bf16. EPI 1: store f32 = res + acc. EPI 2: swiglu.
template <int EPI>
__global__ __launch_bounds__(256) void gemm_bt(
    const unsigned short* __restrict__ A, const unsigned short* __restrict__ B,
    void* __restrict__ Cout, const float* __restrict__ res, int M, int N, int K) {
  __shared__ __align__(16) unsigned short As[128 * 64];
  __shared__ __align__(16) unsigned short Bs[128 * 64];
  const int tid = threadIdx.x;
  const int lane = tid & 63;
  const int w = tid >> 6;
  const int c = lane & 15, g = lane >> 4;
  // bijective XCD swizzle (nwg % 8 == 0 for all our grids)
  const int id = blockIdx.y * gridDim.x + blockIdx.x;
  const int cpx = (gridDim.x * gridDim.y) >> 3;
  const int sid = (id & 7) * cpx + (id >> 3);
  const int bx = sid % gridDim.x;
  const int by = sid / gridDim.x;
  const long m0 = (long)bx * 128;
  const long n0 = (long)by * 128;
  const int wm = (w >> 1) * 64, wn = (w & 1) * 64;

  const f32x4 fzero = {0.f, 0.f, 0.f, 0.f};
  f32x4 acc[4][4];
#pragma unroll
  for (int i = 0; i < 4; ++i)
#pragma unroll
    for (int j = 0; j < 4; ++j) acc[i][j] = fzero;

  const int srow = w * 32 + (lane >> 3);
  const int scol = (lane & 7) * 8;
  const unsigned short* Ag = A + (m0 + srow) * (long)K + scol;
  const unsigned short* Bg = B + (n0 + srow) * (long)K + scol;

  for (int k0 = 0; k0 < K; k0 += 64) {
    __syncthreads();
#pragma unroll
    for (int i = 0; i < 4; ++i) {
      async16(As + (w * 32 + i * 8) * 64, Ag + (long)i * 8 * K + k0);
      async16(Bs + (w * 32 + i * 8) * 64, Bg + (long)i * 8 * K + k0);
    }
    __syncthreads();
#pragma unroll
    for (int kk = 0; kk < 2; ++kk) {
      bf16x8 af[4], bfr[4];
#pragma unroll
      for (int tt = 0; tt < 4; ++tt) {
        af[tt] = *(const bf16x8*)(As + (wm + tt * 16 + c) * 64 + kk * 32 + g * 8);
        bfr[tt] = *(const bf16x8*)(Bs + (wn + tt * 16 + c) * 64 + kk * 32 + g * 8);
      }
#pragma unroll
      for (int i = 0; i < 4; ++i)
#pragma unroll
        for (int j = 0; j < 4; ++j)
          acc[i][j] = __builtin_amdgcn_mfma_f32_16x16x32_bf16(af[i], bfr[j], acc[i][j], 0, 0, 0);
    }
  }

#pragma unroll
  for (int i = 0; i < 4; ++i) {
#pragma unroll
    for (int j = 0; j < 4; ++j) {
      const long row0 = m0 + wm + i * 16 + g * 4;
      const long col = n0 + wn + j * 16 + c;
#pragma unroll
      for (int r = 0; r < 4; ++r) {
        float v = acc[i][j][r];
        if (EPI == 0) {
          ((unsigned short*)Cout)[(row0 + r) * N + col] = f32_bf16(v);
        } else if (EPI == 1) {
          ((float*)Cout)[(row0 + r) * N + col] = res[(row0 + r) * N + col] + v;
        } else {
          float other = __shfl_xor(v, 1);
          if (!(c & 1)) {
            float sg = v / (1.0f + __expf(-v));
            ((unsigned short*)Cout)[(row0 + r) * (long)(N >> 1) + (col >> 1)] =
                f32_bf16(sg * other);
          }
        }
      }
    }
  }
}

// ----------------------------------------------------------- v transpose ----
__global__ __launch_bounds__(256) void transpose_v(
    const unsigned short* __restrict__ qkv, unsigned short* __restrict__ vT) {
  __shared__ __align__(16) unsigned short tile[64][72];
  const int tx = blockIdx.x;
  const int dx = blockIdx.y;
  const int tid = threadIdx.x;
  const int r = tid >> 3, cg = tid & 7;
#pragma unroll
  for (int it = 0; it < 2; ++it) {
    const unsigned short* src =
        qkv + (long)(tx * 64 + r + it * 32) * 3072 + 2560 + dx * 64 + cg * 8;
    *(ushort8*)(&tile[r + it * 32][cg * 8]) = *(const ushort8*)src;
  }
  __syncthreads();
#pragma unroll
  for (int it = 0; it < 2; ++it) {
    int d = r + it * 32;
    ushort8 v;
#pragma unroll
    for (int j = 0; j < 8; ++j) v[j] = tile[cg * 8 + j][d];
    *(ushort8*)(vT + (long)(dx * 64 + d) * 4096 + tx * 64 + cg * 8) = v;
  }
}

// ------------------------------------------------------------- attention ----
// Swapped-operand causal GQA flash attention.
// Block = 8 waves (512 thr) handling q-tile PAIR (pid, 31-pid): waves 0-3 ->
// tile A rows, waves 4-7 -> tile B rows (32 q-rows per wave). Equal work per
// block (66 step-units). K [64][128] and V^T [128][64] double-buffered in LDS
// via global_load_lds with inverse-swizzled source (granule ^= row&7),
// XOR-swizzled reads -> conflict-free. S^T = mfma(K,Q): lane owns q=c; row
// reduce = in-lane + shfl_xor(16,32). P^T in regs IS the 16x16x16 B-fragment:
// PV swapped (O^T = mfma(Vt, Pt)) with zero shuffles.
__global__ __launch_bounds__(512, 2) void attn_kernel(
    const unsigned short* __restrict__ qkv, const unsigned short* __restrict__ vT,
    unsigned short* __restrict__ y) {
  constexpr float SCL = 0.08838834764831845f * 1.4426950408889634f;
  __shared__ __align__(16) unsigned short Kb[2][64 * 128];
  __shared__ __align__(16) unsigned short Vb[2][128 * 64];

  const int tid = threadIdx.x;
  const int lane = tid & 63;
  const int w = tid >> 6;           // 0..7
  const int c = lane & 15, g = lane >> 4;
  const int h = blockIdx.x >> 4;    // head (slow bits -> XCD L2 locality)
  const int pid = blockIdx.x & 15;
  const int kvh = h >> 2;
  const int qt = (w < 4) ? pid : (31 - pid);
  const int q0w = qt * 128 + (w & 3) * 32;
  const int nsteps = 2 * (31 - pid) + 2;

  const f32x4 fzero = {0.f, 0.f, 0.f, 0.f};

  // Q fragments (B-operand: lane holds Q[q = q0w+mt*16+c][d = kk*32+g*8..])
  bf16x8 qf[2][4];
#pragma unroll
  for (int mt = 0; mt < 2; ++mt)
#pragma unroll
    for (int kk = 0; kk < 4; ++kk)
      qf[mt][kk] = *(const bf16x8*)(qkv + (long)(q0w + mt * 16 + c) * 3072 +
                                    h * 128 + kk * 32 + g * 8);

  f32x4 o[2][8];  // O^T: lane q=c, d = dt*16 + g*4 + r
#pragma unroll
  for (int mt = 0; mt < 2; ++mt)
#pragma unroll
    for (int dt = 0; dt < 8; ++dt) o[mt][dt] = fzero;
  float m[2] = {-1e30f, -1e30f}, l[2] = {0.f, 0.f};

  auto stage = [&](int buf, int kv0) {
#pragma unroll
    for (int k = 0; k < 2; ++k) {  // K tile: 1024 granules, 512 thr -> 2 calls
      int G = k * 512 + tid;
      int row = G >> 4, colg = (G & 15) ^ (row & 7);
      async16(&Kb[buf][(k * 512 + (tid & ~63)) * 8],
              qkv + (long)(kv0 + row) * 3072 + 2048 + kvh * 128 + colg * 8);
    }
#pragma unroll
    for (int k = 0; k < 2; ++k) {  // V tile
      int G = k * 512 + tid;
      int row = G >> 3, colg = (G & 7) ^ (row & 7);
      async16(&Vb[buf][(k * 512 + (tid & ~63)) * 8],
              vT + (long)(kvh * 128 + row) * 4096 + kv0 + colg * 8);
    }
  };

  stage(0, 0);
  for (int s = 0; s < nsteps; ++s) {
    const int kv0 = s * 64;
    const int bi = s & 1;
    if (s + 1 < nsteps) {
      stage(bi ^ 1, kv0 + 64);
      asm volatile("s_waitcnt vmcnt(4)" ::: "memory");
    } else {
      asm volatile("s_waitcnt vmcnt(0)" ::: "memory");
    }
    __builtin_amdgcn_s_barrier();
    if (kv0 <= q0w + 31) {
      const unsigned short* Ks = Kb[bi];
      const unsigned short* Vs = Vb[bi];
      // S^T = K Q^T
      f32x4 sv[2][4];
#pragma unroll
      for (int mt = 0; mt < 2; ++mt)
#pragma unroll
        for (int nt = 0; nt < 4; ++nt) sv[mt][nt] = fzero;
#pragma unroll
      for (int kk = 0; kk < 4; ++kk) {
        bf16x8 kf[4];
#pragma unroll
        for (int nt = 0; nt < 4; ++nt)
          kf[nt] = *(const bf16x8*)(Ks + (nt * 16 + c) * 128 +
                                    (((kk * 4 + g) ^ (c & 7)) << 3));
#pragma unroll
        for (int mt = 0; mt < 2; ++mt)
#pragma unroll
          for (int nt = 0; nt < 4; ++nt)
            sv[mt][nt] = __builtin_amdgcn_mfma_f32_16x16x32_bf16(
                kf[nt], qf[mt][kk], sv[mt][nt], 0, 0, 0);
      }
      const bool need_mask = (kv0 + 63 > q0w);
      float al[2];
#pragma unroll
      for (int mt = 0; mt < 2; ++mt) {
        const int qrow = q0w + mt * 16 + c;
#pragma unroll
        for (int nt = 0; nt < 4; ++nt)
#pragma unroll
          for (int r = 0; r < 4; ++r) {
            float xx = sv[mt][nt][r] * SCL;
            if (need_mask && (kv0 + nt * 16 + g * 4 + r > qrow)) xx = -3.0e38f;
            sv[mt][nt][r] = xx;
          }
        float mx = -3.0e38f;
#pragma unroll
        for (int nt = 0; nt < 4; ++nt)
#pragma unroll
          for (int r = 0; r < 4; ++r) mx = fmaxf(mx, sv[mt][nt][r]);
        mx = fmaxf(mx, __shfl_xor(mx, 16));
        mx = fmaxf(mx, __shfl_xor(mx, 32));
        const float mn = fmaxf(m[mt], mx);
        const float a = exp2f(m[mt] - mn);
        m[mt] = mn;
        al[mt] = a;
        float rs = 0.f;
#pragma unroll
        for (int nt = 0; nt < 4; ++nt)
#pragma unroll
          for (int r = 0; r < 4; ++r) {
            float p = exp2f(sv[mt][nt][r] - mn);
            sv[mt][nt][r] = p;
            rs += p;
          }
        rs += __shfl_xor(rs, 16);
        rs += __shfl_xor(rs, 32);
        l[mt] = l[mt] * a + rs;
#pragma unroll
        for (int dt = 0; dt < 8; ++dt) o[mt][dt] *= al[mt];
      }
      // PV: O^T += V^T_frag x P^T_frag (16x16x16, P already per-lane)
#pragma unroll
      for (int nt = 0; nt < 4; ++nt) {
        bf16x4 pb[2];
#pragma unroll
        for (int mt = 0; mt < 2; ++mt) {
          int lo_, hi_;
          float s0 = sv[mt][nt][0], s1 = sv[mt][nt][1];
          float s2 = sv[mt][nt][2], s3 = sv[mt][nt][3];
          asm("v_cvt_pk_bf16_f32 %0, %1, %2" : "=v"(lo_) : "v"(s0), "v"(s1));
          asm("v_cvt_pk_bf16_f32 %0, %1, %2" : "=v"(hi_) : "v"(s2), "v"(s3));
          int2 pk = make_int2(lo_, hi_);
          pb[mt] = __builtin_bit_cast(bf16x4, pk);
        }
#pragma unroll
        for (int dt = 0; dt < 8; ++dt) {
          bf16x4 vt = *(const bf16x4*)(Vs + (dt * 16 + c) * 64 +
                                       (((nt * 2 + (g >> 1)) ^ (c & 7)) << 3) +
                                       (g & 1) * 4);
          o[0][dt] = mfma16(vt, pb[0], o[0][dt]);
          o[1][dt] = mfma16(vt, pb[1], o[1][dt]);
        }
      }
    }
    __builtin_amdgcn_s_barrier();
  }
  // epilogue: normalize + store (8B per store, 4 consecutive d per lane)
#pragma unroll
  for (int mt = 0; mt < 2; ++mt) {
    const float inv = 1.0f / l[mt];
    const long qrow = q0w + mt * 16 + c;
#pragma unroll
    for (int dt = 0; dt < 8; ++dt) {
      us4 st;
      st[0] = f32_bf16(o[mt][dt][0] * inv);
      st[1] = f32_bf16(o[mt][dt][1] * inv);
      st[2] = f32_bf16(o[mt][dt][2] * inv);
      st[3] = f32_bf16(o[mt][dt][3] * inv);
      *(us4*)(y + qrow * 2048 + h * 128 + dt * 16 + g * 4) = st;
    }
  }
}

// ------------------------------------------------------------------ host ----
extern "C" void kernel_launch(void* const* d_in, const int* in_sizes, int n_in,
                              void* d_out, int out_size, void* d_ws, size_t ws_size,
                              hipStream_t stream) {
  (void)in_sizes; (void)n_in; (void)out_size; (void)ws_size;
  const float* x      = (const float*)d_in[0];
  const float* attn_w = (const float*)d_in[2];
  const float* wq     = (const float*)d_in[3];
  const float* wk     = (const float*)d_in[4];
  const float* wv     = (const float*)d_in[5];
  const float* wo     = (const float*)d_in[6];
  const float* ffn_w  = (const float*)d_in[7];
  const float* wg     = (const float*)d_in[8];
  const float* wu     = (const float*)d_in[9];
  const float* wd     = (const float*)d_in[10];
  float* out = (float*)d_out;

  char* ws = (char*)d_ws;
  size_t off = 0;
  auto alloc = [&](size_t bytes) {
    char* p = ws + off;
    off += (bytes + 255) & ~(size_t)255;
    return p;
  };
  float2* rope_tab        = (float2*)alloc(4096UL * 64 * sizeof(float2));
  unsigned short* wqkv_b  = (unsigned short*)alloc(3072UL * 2048 * 2);
  unsigned short* wo_b    = (unsigned short*)alloc(2048UL * 2048 * 2);
  unsigned short* wgu_b   = (unsigned short*)alloc(16384UL * 2048 * 2);
  unsigned short* wd_b    = (unsigned short*)alloc(2048UL * 8192 * 2);
  unsigned short* h_b     = (unsigned short*)alloc(4096UL * 2048 * 2);
  unsigned short* qkv_b   = (unsigned short*)alloc(4096UL * 3072 * 2);
  unsigned short* vT_b    = (unsigned short*)alloc(512UL * 4096 * 2);
  unsigned short* y_b     = (unsigned short*)alloc(4096UL * 2048 * 2);
  float* r1               = (float*)alloc(4096UL * 2048 * 4);
  unsigned short* t_b     = (unsigned short*)alloc(4096UL * 8192 * 2);

  // weight casts
  cast_bf16_kernel<<<2048, 256, 0, stream>>>(wq, wqkv_b, 524288);
  cast_bf16_kernel<<<512, 256, 0, stream>>>(wk, wqkv_b + 2048L * 2048, 131072);
  cast_bf16_kernel<<<512, 256, 0, stream>>>(wv, wqkv_b + 2560L * 2048, 131072);
  cast_bf16_kernel<<<2048, 256, 0, stream>>>(wo, wo_b, 524288);
  cast_gu_kernel<<<16384, 256, 0, stream>>>(wg, wu, wgu_b);
  cast_bf16_kernel<<<8192, 256, 0, stream>>>(wd, wd_b, 2097152);
  rope_table_kernel<<<1024, 256, 0, stream>>>(rope_tab);

  // attn branch
  rmsnorm_kernel<<<4096, 256, 0, stream>>>(x, attn_w, h_b);
  {
    dim3 grid(32, 24);
    gemm_bt<0><<<grid, 256, 0, stream>>>(h_b, wqkv_b, qkv_b, nullptr, 4096, 3072, 2048);
  }
  rope_apply_kernel<<<4096, 256, 0, stream>>>(qkv_b, rope_tab);
  {
    dim3 grid(64, 8);
    transpose_v<<<grid, 256, 0, stream>>>(qkv_b, vT_b);
  }
  attn_kernel<<<256, 512, 0, stream>>>(qkv_b, vT_b, y_b);
  {
    dim3 grid(32, 16);
    gemm_bt<1><<<grid, 256, 0, stream>>>(y_b, wo_b, r1, x, 4096, 2048, 2048);
  }

  // ffn branch
  rmsnorm_kernel<<<4096, 256, 0, stream>>>(r1, ffn_w, h_b);
  {
    dim3 grid(32, 128);
    gemm_bt<2><<<grid, 256, 0, stream>>>(h_b, wgu_b, t_b, nullptr, 4096, 16384, 2048);
  }
  {
    dim3 grid(32, 16);
    gemm_bt<1><<<grid, 256, 0, stream>>>(t_b, wd_b, out, r1, 4096, 2048, 8192);
  }
}

// Round 3
// 986.465 us; speedup vs baseline: 1.4715x; 1.1897x over previous
//
#include <hip/hip_runtime.h>
#include <math.h>

#define DEVI static __device__ __forceinline__

typedef __attribute__((ext_vector_type(8))) short bf16x8;
typedef __attribute__((ext_vector_type(4))) short bf16x4;
typedef __attribute__((ext_vector_type(8))) unsigned short ushort8;
typedef __attribute__((ext_vector_type(4))) unsigned short us4;
typedef __attribute__((ext_vector_type(4))) float f32x4;

DEVI unsigned short f32_bf16(float f) {
  unsigned int u = __float_as_uint(f);
  u += 0x7fffu + ((u >> 16) & 1u);
  return (unsigned short)(u >> 16);
}
DEVI float bf16_f32(unsigned short h) {
  return __uint_as_float(((unsigned int)h) << 16);
}

DEVI void async16(void* lds, const void* g) {
  __builtin_amdgcn_global_load_lds(
      (const __attribute__((address_space(1))) void*)g,
      (__attribute__((address_space(3))) void*)lds,
      16, 0, 0);
}

#if __has_builtin(__builtin_amdgcn_mfma_f32_16x16x16bf16_1k)
DEVI f32x4 mfma16(bf16x4 a, bf16x4 b, f32x4 c) {
  return __builtin_amdgcn_mfma_f32_16x16x16bf16_1k(a, b, c, 0, 0, 0);
}
#else
DEVI f32x4 mfma16(bf16x4 a, bf16x4 b, f32x4 c) {
  asm volatile("v_mfma_f32_16x16x16_bf16 %0, %1, %2, %0" : "+v"(c) : "v"(a), "v"(b));
  return c;
}
#endif

// ---------------------------------------------------------------- casts ----
__global__ __launch_bounds__(256) void cast_bf16_kernel(
    const float* __restrict__ src, unsigned short* __restrict__ dst, long n8) {
  long i = (long)blockIdx.x * 256 + threadIdx.x;
  if (i >= n8) return;
  const float4 a = *(const float4*)(src + i * 8);
  const float4 b = *(const float4*)(src + i * 8 + 4);
  ushort8 o;
  o[0] = f32_bf16(a.x); o[1] = f32_bf16(a.y); o[2] = f32_bf16(a.z); o[3] = f32_bf16(a.w);
  o[4] = f32_bf16(b.x); o[5] = f32_bf16(b.y); o[6] = f32_bf16(b.z); o[7] = f32_bf16(b.w);
  *(ushort8*)(dst + i * 8) = o;
}

// gate/up interleave: dst row 2j = gate j, row 2j+1 = up j.  [16384][2048]
__global__ __launch_bounds__(256) void cast_gu_kernel(
    const float* __restrict__ gate, const float* __restrict__ up,
    unsigned short* __restrict__ dst) {
  long i = (long)blockIdx.x * 256 + threadIdx.x;
  long row = i >> 8;
  long col = (i & 255) * 8;
  const float* src = ((row & 1) ? up : gate) + ((row >> 1) << 11) + col;
  const float4 a = *(const float4*)(src);
  const float4 b = *(const float4*)(src + 4);
  ushort8 o;
  o[0] = f32_bf16(a.x); o[1] = f32_bf16(a.y); o[2] = f32_bf16(a.z); o[3] = f32_bf16(a.w);
  o[4] = f32_bf16(b.x); o[5] = f32_bf16(b.y); o[6] = f32_bf16(b.z); o[7] = f32_bf16(b.w);
  *(ushort8*)(dst + i * 8) = o;
}

// ----------------------------------------------------------------- rope ----
__global__ __launch_bounds__(256) void rope_table_kernel(float2* __restrict__ tab) {
  int idx = blockIdx.x * 256 + threadIdx.x;
  int t = idx >> 6, i = idx & 63;
  float inv = __expf(-(float)(2 * i) * (1.0f / 128.0f) * 13.122363377404328f);
  float f = (float)t * inv;
  tab[idx] = make_float2(cosf(f), sinf(f));
}

__global__ __launch_bounds__(256) void rope_apply_kernel(
    unsigned short* __restrict__ qkv, const float2* __restrict__ tab) {
  const int row = blockIdx.x;
  const int tid = threadIdx.x;
#pragma unroll
  for (int it = 0; it < 5; ++it) {
    int p = tid + it * 256;
    int head = p >> 6, i = p & 63;
    int col = (p < 1024) ? (head * 128 + 2 * i) : (2048 + (head - 16) * 128 + 2 * i);
    unsigned short* ptr = qkv + (long)row * 3072 + col;
    float a = bf16_f32(ptr[0]), b = bf16_f32(ptr[1]);
    float2 cs = tab[row * 64 + i];
    float a2 = a * cs.x - b * cs.y;
    float b2 = a * cs.y + b * cs.x;
    ptr[0] = f32_bf16(a2);
    ptr[1] = f32_bf16(b2);
  }
}

// -------------------------------------------------------------- rmsnorm ----
__global__ __launch_bounds__(256) void rmsnorm_kernel(
    const float* __restrict__ x, const float* __restrict__ wgt,
    unsigned short* __restrict__ out) {
  __shared__ float red[4];
  const int row = blockIdx.x;
  const int tid = threadIdx.x;
  const float* xr = x + (long)row * 2048 + tid * 8;
  const float4 v0 = *(const float4*)(xr);
  const float4 v1 = *(const float4*)(xr + 4);
  float ss = v0.x * v0.x + v0.y * v0.y + v0.z * v0.z + v0.w * v0.w +
             v1.x * v1.x + v1.y * v1.y + v1.z * v1.z + v1.w * v1.w;
#pragma unroll
  for (int off = 1; off < 64; off <<= 1) ss += __shfl_xor(ss, off);
  if ((tid & 63) == 0) red[tid >> 6] = ss;
  __syncthreads();
  float tot = red[0] + red[1] + red[2] + red[3];
  float sc = rsqrtf(tot * (1.0f / 2048.0f) + 1e-5f);
  const float4 w0 = *(const float4*)(wgt + tid * 8);
  const float4 w1 = *(const float4*)(wgt + tid * 8 + 4);
  ushort8 o;
  o[0] = f32_bf16(v0.x * sc * w0.x); o[1] = f32_bf16(v0.y * sc * w0.y);
  o[2] = f32_bf16(v0.z * sc * w0.z); o[3] = f32_bf16(v0.w * sc * w0.w);
  o[4] = f32_bf16(v1.x * sc * w1.x); o[5] = f32_bf16(v1.y * sc * w1.y);
  o[6] = f32_bf16(v1.z * sc * w1.z); o[7] = f32_bf16(v1.w * sc * w1.w);
  *(ushort8*)(out + (long)row * 2048 + tid * 8) = o;
}

// ------------------------------------------------------ 8-phase gemm ----
// C[M,N] = A[M,K] @ B[N,K]^T, bf16 in, f32 acc. 256xBN tile, BK=64,
// 8 waves (WMxWN), double-buffered LDS, XOR-swizzled (write side via
// inverse-swizzled global source, read side via swizzled ds_read addr).
// 4 phases per K-tile, counted waits: vmcnt(0) only at phase 3 (loads were
// issued at phases 0/1 -> ~2.5 phases of flight), lgkmcnt(0)+sched_barrier
// before each MFMA cluster, setprio(1) around MFMA.
// EPI 0: store bf16. EPI 1: store f32 = res + acc. EPI 2: swiglu.
template <int BN, int EPI>
__global__ __launch_bounds__(512, 2) void gemm8p(
    const unsigned short* __restrict__ A, const unsigned short* __restrict__ B,
    void* __restrict__ Cout, const float* __restrict__ res, int M, int N, int K) {
  constexpr int WN = (BN == 256) ? 4 : 2;  // waves along N
  constexpr int WM = 8 / WN;               // waves along M
  constexpr int WTM = 256 / WM;            // 128 or 64
  constexpr int WTN = BN / WN;             // 64
  constexpr int MF = WTM / 16;             // 8 or 4
  constexpr int NF = WTN / 16;             // 4
  constexpr int MFH = MF / 2, NFH = NF / 2;
  constexpr int B_LOADS = (BN * 8) / 512;  // 4 or 2

  __shared__ __align__(16) unsigned short As[2][256 * 64];
  __shared__ __align__(16) unsigned short Bs[2][BN * 64];

  const int tid = threadIdx.x;
  const int lane = tid & 63;
  const int w = tid >> 6;
  const int c = lane & 15, g = lane >> 4;
  const int c7 = c & 7;
  const int wm = (w / WN) * WTM, wn = (w % WN) * WTN;

  // bijective XCD swizzle (all grids have nwg % 8 == 0)
  const int id = blockIdx.y * gridDim.x + blockIdx.x;
  const int cpx = (gridDim.x * gridDim.y) >> 3;
  const int sid = (id & 7) * cpx + (id >> 3);
  const int bx = sid % gridDim.x;
  const int by = sid / gridDim.x;
  const long m0 = (long)bx * 256;
  const long n0 = (long)by * BN;

  const f32x4 fzero = {0.f, 0.f, 0.f, 0.f};
  f32x4 acc[MF][NF];
#pragma unroll
  for (int i = 0; i < MF; ++i)
#pragma unroll
    for (int j = 0; j < NF; ++j) acc[i][j] = fzero;

  auto stageA = [&](int buf, int k0) {
#pragma unroll
    for (int q = 0; q < 4; ++q) {
      int G = q * 512 + tid;
      int r = G >> 3;
      int cg = (G & 7) ^ (r & 7);
      async16(&As[buf][(q * 512 + (tid & ~63)) * 8],
              A + (m0 + r) * (long)K + k0 + cg * 8);
    }
  };
  auto stageB = [&](int buf, int k0) {
#pragma unroll
    for (int q = 0; q < B_LOADS; ++q) {
      int G = q * 512 + tid;
      int r = G >> 3;
      int cg = (G & 7) ^ (r & 7);
      async16(&Bs[buf][(q * 512 + (tid & ~63)) * 8],
              B + (n0 + r) * (long)K + k0 + cg * 8);
    }
  };

  stageA(0, 0);
  stageB(0, 0);
  asm volatile("s_waitcnt vmcnt(0)" ::: "memory");
  __builtin_amdgcn_s_barrier();

  const int NT = K >> 6;
  const int swz0 = (g ^ c7) << 3;
  const int swz1 = ((4 + g) ^ c7) << 3;

  for (int t = 0; t < NT; ++t) {
    const int cur = t & 1;
    const unsigned short* Ab = As[cur];
    const unsigned short* Bb = Bs[cur];
#pragma unroll
    for (int ph = 0; ph < 4; ++ph) {
      const int mh = ph >> 1, nh = ph & 1;
      bf16x8 af[MFH][2], bfr[NFH][2];
#pragma unroll
      for (int mf = 0; mf < MFH; ++mf) {
        const int row = wm + (mh * MFH + mf) * 16 + c;
        af[mf][0] = *(const bf16x8*)(Ab + row * 64 + swz0);
        af[mf][1] = *(const bf16x8*)(Ab + row * 64 + swz1);
      }
#pragma unroll
      for (int nf = 0; nf < NFH; ++nf) {
        const int row = wn + (nh * NFH + nf) * 16 + c;
        bfr[nf][0] = *(const bf16x8*)(Bb + row * 64 + swz0);
        bfr[nf][1] = *(const bf16x8*)(Bb + row * 64 + swz1);
      }
      if (t + 1 < NT) {
        if (ph == 0) stageA(cur ^ 1, (t + 1) * 64);
        if (ph == 1) stageB(cur ^ 1, (t + 1) * 64);
      }
      __builtin_amdgcn_s_barrier();
      asm volatile("s_waitcnt lgkmcnt(0)" ::: "memory");
      __builtin_amdgcn_sched_barrier(0);
      __builtin_amdgcn_s_setprio(1);
#pragma unroll
      for (int kk = 0; kk < 2; ++kk)
#pragma unroll
        for (int mf = 0; mf < MFH; ++mf)
#pragma unroll
          for (int nf = 0; nf < NFH; ++nf)
            acc[mh * MFH + mf][nh * NFH + nf] =
                __builtin_amdgcn_mfma_f32_16x16x32_bf16(
                    af[mf][kk], bfr[nf][kk], acc[mh * MFH + mf][nh * NFH + nf],
                    0, 0, 0);
      __builtin_amdgcn_s_setprio(0);
      if (ph == 3) asm volatile("s_waitcnt vmcnt(0)" ::: "memory");
      __builtin_amdgcn_s_barrier();
    }
  }

#pragma unroll
  for (int i = 0; i < MF; ++i) {
#pragma unroll
    for (int j = 0; j < NF; ++j) {
      const long row0 = m0 + wm + i * 16 + g * 4;
      const long col = n0 + wn + j * 16 + c;
#pragma unroll
      for (int r = 0; r < 4; ++r) {
        float v = acc[i][j][r];
        if (EPI == 0) {
          ((unsigned short*)Cout)[(row0 + r) * N + col] = f32_bf16(v);
        } else if (EPI == 1) {
          ((float*)Cout)[(row0 + r) * N + col] = res[(row0 + r) * N + col] + v;
        } else {
          float other = __shfl_xor(v, 1);
          if (!(c & 1)) {
            float sg = v / (1.0f + __expf(-v));
            ((unsigned short*)Cout)[(row0 + r) * (long)(N >> 1) + (col >> 1)] =
                f32_bf16(sg * other);
          }
        }
      }
    }
  }
}

// ----------------------------------------------------------- v transpose ----
__global__ __launch_bounds__(256) void transpose_v(
    const unsigned short* __restrict__ qkv, unsigned short* __restrict__ vT) {
  __shared__ __align__(16) unsigned short tile[64][72];
  const int tx = blockIdx.x;
  const int dx = blockIdx.y;
  const int tid = threadIdx.x;
  const int r = tid >> 3, cg = tid & 7;
#pragma unroll
  for (int it = 0; it < 2; ++it) {
    const unsigned short* src =
        qkv + (long)(tx * 64 + r + it * 32) * 3072 + 2560 + dx * 64 + cg * 8;
    *(ushort8*)(&tile[r + it * 32][cg * 8]) = *(const ushort8*)src;
  }
  __syncthreads();
#pragma unroll
  for (int it = 0; it < 2; ++it) {
    int d = r + it * 32;
    ushort8 v;
#pragma unroll
    for (int j = 0; j < 8; ++j) v[j] = tile[cg * 8 + j][d];
    *(ushort8*)(vT + (long)(dx * 64 + d) * 4096 + tx * 64 + cg * 8) = v;
  }
}

// ------------------------------------------------------------- attention ----
// Swapped-operand causal GQA flash attention (see round-1 notes).
__global__ __launch_bounds__(512, 2) void attn_kernel(
    const unsigned short* __restrict__ qkv, const unsigned short* __restrict__ vT,
    unsigned short* __restrict__ y) {
  constexpr float SCL = 0.08838834764831845f * 1.4426950408889634f;
  __shared__ __align__(16) unsigned short Kb[2][64 * 128];
  __shared__ __align__(16) unsigned short Vb[2][128 * 64];

  const int tid = threadIdx.x;
  const int lane = tid & 63;
  const int w = tid >> 6;
  const int c = lane & 15, g = lane >> 4;
  const int h = blockIdx.x >> 4;
  const int pid = blockIdx.x & 15;
  const int kvh = h >> 2;
  const int qt = (w < 4) ? pid : (31 - pid);
  const int q0w = qt * 128 + (w & 3) * 32;
  const int nsteps = 2 * (31 - pid) + 2;

  const f32x4 fzero = {0.f, 0.f, 0.f, 0.f};

  bf16x8 qf[2][4];
#pragma unroll
  for (int mt = 0; mt < 2; ++mt)
#pragma unroll
    for (int kk = 0; kk < 4; ++kk)
      qf[mt][kk] = *(const bf16x8*)(qkv + (long)(q0w + mt * 16 + c) * 3072 +
                                    h * 128 + kk * 32 + g * 8);

  f32x4 o[2][8];
#pragma unroll
  for (int mt = 0; mt < 2; ++mt)
#pragma unroll
    for (int dt = 0; dt < 8; ++dt) o[mt][dt] = fzero;
  float m[2] = {-1e30f, -1e30f}, l[2] = {0.f, 0.f};

  auto stage = [&](int buf, int kv0) {
#pragma unroll
    for (int k = 0; k < 2; ++k) {
      int G = k * 512 + tid;
      int row = G >> 4, colg = (G & 15) ^ (row & 7);
      async16(&Kb[buf][(k * 512 + (tid & ~63)) * 8],
              qkv + (long)(kv0 + row) * 3072 + 2048 + kvh * 128 + colg * 8);
    }
#pragma unroll
    for (int k = 0; k < 2; ++k) {
      int G = k * 512 + tid;
      int row = G >> 3, colg = (G & 7) ^ (row & 7);
      async16(&Vb[buf][(k * 512 + (tid & ~63)) * 8],
              vT + (long)(kvh * 128 + row) * 4096 + kv0 + colg * 8);
    }
  };

  stage(0, 0);
  for (int s = 0; s < nsteps; ++s) {
    const int kv0 = s * 64;
    const int bi = s & 1;
    if (s + 1 < nsteps) {
      stage(bi ^ 1, kv0 + 64);
      asm volatile("s_waitcnt vmcnt(4)" ::: "memory");
    } else {
      asm volatile("s_waitcnt vmcnt(0)" ::: "memory");
    }
    __builtin_amdgcn_s_barrier();
    if (kv0 <= q0w + 31) {
      const unsigned short* Ks = Kb[bi];
      const unsigned short* Vs = Vb[bi];
      f32x4 sv[2][4];
#pragma unroll
      for (int mt = 0; mt < 2; ++mt)
#pragma unroll
        for (int nt = 0; nt < 4; ++nt) sv[mt][nt] = fzero;
#pragma unroll
      for (int kk = 0; kk < 4; ++kk) {
        bf16x8 kf[4];
#pragma unroll
        for (int nt = 0; nt < 4; ++nt)
          kf[nt] = *(const bf16x8*)(Ks + (nt * 16 + c) * 128 +
                                    (((kk * 4 + g) ^ (c & 7)) << 3));
#pragma unroll
        for (int mt = 0; mt < 2; ++mt)
#pragma unroll
          for (int nt = 0; nt < 4; ++nt)
            sv[mt][nt] = __builtin_amdgcn_mfma_f32_16x16x32_bf16(
                kf[nt], qf[mt][kk], sv[mt][nt], 0, 0, 0);
      }
      const bool need_mask = (kv0 + 63 > q0w);
      float al[2];
#pragma unroll
      for (int mt = 0; mt < 2; ++mt) {
        const int qrow = q0w + mt * 16 + c;
#pragma unroll
        for (int nt = 0; nt < 4; ++nt)
#pragma unroll
          for (int r = 0; r < 4; ++r) {
            float xx = sv[mt][nt][r] * SCL;
            if (need_mask && (kv0 + nt * 16 + g * 4 + r > qrow)) xx = -3.0e38f;
            sv[mt][nt][r] = xx;
          }
        float mx = -3.0e38f;
#pragma unroll
        for (int nt = 0; nt < 4; ++nt)
#pragma unroll
          for (int r = 0; r < 4; ++r) mx = fmaxf(mx, sv[mt][nt][r]);
        mx = fmaxf(mx, __shfl_xor(mx, 16));
        mx = fmaxf(mx, __shfl_xor(mx, 32));
        const float mn = fmaxf(m[mt], mx);
        const float a = exp2f(m[mt] - mn);
        m[mt] = mn;
        al[mt] = a;
        float rs = 0.f;
#pragma unroll
        for (int nt = 0; nt < 4; ++nt)
#pragma unroll
          for (int r = 0; r < 4; ++r) {
            float p = exp2f(sv[mt][nt][r] - mn);
            sv[mt][nt][r] = p;
            rs += p;
          }
        rs += __shfl_xor(rs, 16);
        rs += __shfl_xor(rs, 32);
        l[mt] = l[mt] * a + rs;
#pragma unroll
        for (int dt = 0; dt < 8; ++dt) o[mt][dt] *= al[mt];
      }
#pragma unroll
      for (int nt = 0; nt < 4; ++nt) {
        bf16x4 pb[2];
#pragma unroll
        for (int mt = 0; mt < 2; ++mt) {
          int lo_, hi_;
          float s0 = sv[mt][nt][0], s1 = sv[mt][nt][1];
          float s2 = sv[mt][nt][2], s3 = sv[mt][nt][3];
          asm("v_cvt_pk_bf16_f32 %0, %1, %2" : "=v"(lo_) : "v"(s0), "v"(s1));
          asm("v_cvt_pk_bf16_f32 %0, %1, %2" : "=v"(hi_) : "v"(s2), "v"(s3));
          int2 pk = make_int2(lo_, hi_);
          pb[mt] = __builtin_bit_cast(bf16x4, pk);
        }
#pragma unroll
        for (int dt = 0; dt < 8; ++dt) {
          bf16x4 vt = *(const bf16x4*)(Vs + (dt * 16 + c) * 64 +
                                       (((nt * 2 + (g >> 1)) ^ (c & 7)) << 3) +
                                       (g & 1) * 4);
          o[0][dt] = mfma16(vt, pb[0], o[0][dt]);
          o[1][dt] = mfma16(vt, pb[1], o[1][dt]);
        }
      }
    }
    __builtin_amdgcn_s_barrier();
  }
#pragma unroll
  for (int mt = 0; mt < 2; ++mt) {
    const float inv = 1.0f / l[mt];
    const long qrow = q0w + mt * 16 + c;
#pragma unroll
    for (int dt = 0; dt < 8; ++dt) {
      us4 st;
      st[0] = f32_bf16(o[mt][dt][0] * inv);
      st[1] = f32_bf16(o[mt][dt][1] * inv);
      st[2] = f32_bf16(o[mt][dt][2] * inv);
      st[3] = f32_bf16(o[mt][dt][3] * inv);
      *(us4*)(y + qrow * 2048 + h * 128 + dt * 16 + g * 4) = st;
    }
  }
}

// ------------------------------------------------------------------ host ----
extern "C" void kernel_launch(void* const* d_in, const int* in_sizes, int n_in,
                              void* d_out, int out_size, void* d_ws, size_t ws_size,
                              hipStream_t stream) {
  (void)in_sizes; (void)n_in; (void)out_size; (void)ws_size;
  const float* x      = (const float*)d_in[0];
  const float* attn_w = (const float*)d_in[2];
  const float* wq     = (const float*)d_in[3];
  const float* wk     = (const float*)d_in[4];
  const float* wv     = (const float*)d_in[5];
  const float* wo     = (const float*)d_in[6];
  const float* ffn_w  = (const float*)d_in[7];
  const float* wg     = (const float*)d_in[8];
  const float* wu     = (const float*)d_in[9];
  const float* wd     = (const float*)d_in[10];
  float* out = (float*)d_out;

  char* ws = (char*)d_ws;
  size_t off = 0;
  auto alloc = [&](size_t bytes) {
    char* p = ws + off;
    off += (bytes + 255) & ~(size_t)255;
    return p;
  };
  float2* rope_tab        = (float2*)alloc(4096UL * 64 * sizeof(float2));
  unsigned short* wqkv_b  = (unsigned short*)alloc(3072UL * 2048 * 2);
  unsigned short* wo_b    = (unsigned short*)alloc(2048UL * 2048 * 2);
  unsigned short* wgu_b   = (unsigned short*)alloc(16384UL * 2048 * 2);
  unsigned short* wd_b    = (unsigned short*)alloc(2048UL * 8192 * 2);
  unsigned short* h_b     = (unsigned short*)alloc(4096UL * 2048 * 2);
  unsigned short* qkv_b   = (unsigned short*)alloc(4096UL * 3072 * 2);
  unsigned short* vT_b    = (unsigned short*)alloc(512UL * 4096 * 2);
  unsigned short* y_b     = (unsigned short*)alloc(4096UL * 2048 * 2);
  float* r1               = (float*)alloc(4096UL * 2048 * 4);
  unsigned short* t_b     = (unsigned short*)alloc(4096UL * 8192 * 2);

  // weight casts
  cast_bf16_kernel<<<2048, 256, 0, stream>>>(wq, wqkv_b, 524288);
  cast_bf16_kernel<<<512, 256, 0, stream>>>(wk, wqkv_b + 2048L * 2048, 131072);
  cast_bf16_kernel<<<512, 256, 0, stream>>>(wv, wqkv_b + 2560L * 2048, 131072);
  cast_bf16_kernel<<<2048, 256, 0, stream>>>(wo, wo_b, 524288);
  cast_gu_kernel<<<16384, 256, 0, stream>>>(wg, wu, wgu_b);
  cast_bf16_kernel<<<8192, 256, 0, stream>>>(wd, wd_b, 2097152);
  rope_table_kernel<<<1024, 256, 0, stream>>>(rope_tab);

  // attn branch
  rmsnorm_kernel<<<4096, 256, 0, stream>>>(x, attn_w, h_b);
  {
    dim3 grid(16, 12);
    gemm8p<256, 0><<<grid, 512, 0, stream>>>(h_b, wqkv_b, qkv_b, nullptr, 4096, 3072, 2048);
  }
  rope_apply_kernel<<<4096, 256, 0, stream>>>(qkv_b, rope_tab);
  {
    dim3 grid(64, 8);
    transpose_v<<<grid, 256, 0, stream>>>(qkv_b, vT_b);
  }
  attn_kernel<<<256, 512, 0, stream>>>(qkv_b, vT_b, y_b);
  {
    dim3 grid(16, 16);
    gemm8p<128, 1><<<grid, 512, 0, stream>>>(y_b, wo_b, r1, x, 4096, 2048, 2048);
  }

  // ffn branch
  rmsnorm_kernel<<<4096, 256, 0, stream>>>(r1, ffn_w, h_b);
  {
    dim3 grid(16, 64);
    gemm8p<256, 2><<<grid, 512, 0, stream>>>(h_b, wgu_b, t_b, nullptr, 4096, 16384, 2048);
  }
  {
    dim3 grid(16, 16);
    gemm8p<128, 1><<<grid, 512, 0, stream>>>(t_b, wd_b, out, r1, 4096, 2048, 8192);
  }
}

// Round 4
// 956.561 us; speedup vs baseline: 1.5175x; 1.0313x over previous
//
#include <hip/hip_runtime.h>
#include <math.h>

#define DEVI static __device__ __forceinline__

typedef __attribute__((ext_vector_type(8))) short bf16x8;
typedef __attribute__((ext_vector_type(4))) short bf16x4;
typedef __attribute__((ext_vector_type(8))) unsigned short ushort8;
typedef __attribute__((ext_vector_type(4))) unsigned short us4;
typedef __attribute__((ext_vector_type(4))) float f32x4;

DEVI unsigned short f32_bf16(float f) {
  unsigned int u = __float_as_uint(f);
  u += 0x7fffu + ((u >> 16) & 1u);
  return (unsigned short)(u >> 16);
}
DEVI float bf16_f32(unsigned short h) {
  return __uint_as_float(((unsigned int)h) << 16);
}

DEVI void async16(void* lds, const void* g) {
  __builtin_amdgcn_global_load_lds(
      (const __attribute__((address_space(1))) void*)g,
      (__attribute__((address_space(3))) void*)lds,
      16, 0, 0);
}

#if __has_builtin(__builtin_amdgcn_mfma_f32_16x16x16bf16_1k)
DEVI f32x4 mfma16(bf16x4 a, bf16x4 b, f32x4 c) {
  return __builtin_amdgcn_mfma_f32_16x16x16bf16_1k(a, b, c, 0, 0, 0);
}
#else
DEVI f32x4 mfma16(bf16x4 a, bf16x4 b, f32x4 c) {
  asm volatile("v_mfma_f32_16x16x16_bf16 %0, %1, %2, %0" : "+v"(c) : "v"(a), "v"(b));
  return c;
}
#endif

// ---------------------------------------------------------------- casts ----
__global__ __launch_bounds__(256) void cast_bf16_kernel(
    const float* __restrict__ src, unsigned short* __restrict__ dst, long n8) {
  long i = (long)blockIdx.x * 256 + threadIdx.x;
  if (i >= n8) return;
  const float4 a = *(const float4*)(src + i * 8);
  const float4 b = *(const float4*)(src + i * 8 + 4);
  ushort8 o;
  o[0] = f32_bf16(a.x); o[1] = f32_bf16(a.y); o[2] = f32_bf16(a.z); o[3] = f32_bf16(a.w);
  o[4] = f32_bf16(b.x); o[5] = f32_bf16(b.y); o[6] = f32_bf16(b.z); o[7] = f32_bf16(b.w);
  *(ushort8*)(dst + i * 8) = o;
}

// gate/up interleave: dst row 2j = gate j, row 2j+1 = up j.  [16384][2048]
__global__ __launch_bounds__(256) void cast_gu_kernel(
    const float* __restrict__ gate, const float* __restrict__ up,
    unsigned short* __restrict__ dst) {
  long i = (long)blockIdx.x * 256 + threadIdx.x;
  long row = i >> 8;
  long col = (i & 255) * 8;
  const float* src = ((row & 1) ? up : gate) + ((row >> 1) << 11) + col;
  const float4 a = *(const float4*)(src);
  const float4 b = *(const float4*)(src + 4);
  ushort8 o;
  o[0] = f32_bf16(a.x); o[1] = f32_bf16(a.y); o[2] = f32_bf16(a.z); o[3] = f32_bf16(a.w);
  o[4] = f32_bf16(b.x); o[5] = f32_bf16(b.y); o[6] = f32_bf16(b.z); o[7] = f32_bf16(b.w);
  *(ushort8*)(dst + i * 8) = o;
}

// ----------------------------------------------------------------- rope ----
__global__ __launch_bounds__(256) void rope_table_kernel(float2* __restrict__ tab) {
  int idx = blockIdx.x * 256 + threadIdx.x;
  int t = idx >> 6, i = idx & 63;
  float inv = __expf(-(float)(2 * i) * (1.0f / 128.0f) * 13.122363377404328f);
  float f = (float)t * inv;
  tab[idx] = make_float2(cosf(f), sinf(f));
}

__global__ __launch_bounds__(256) void rope_apply_kernel(
    unsigned short* __restrict__ qkv, const float2* __restrict__ tab) {
  const int row = blockIdx.x;
  const int tid = threadIdx.x;
#pragma unroll
  for (int it = 0; it < 5; ++it) {
    int p = tid + it * 256;
    int head = p >> 6, i = p & 63;
    int col = (p < 1024) ? (head * 128 + 2 * i) : (2048 + (head - 16) * 128 + 2 * i);
    unsigned short* ptr = qkv + (long)row * 3072 + col;
    float a = bf16_f32(ptr[0]), b = bf16_f32(ptr[1]);
    float2 cs = tab[row * 64 + i];
    float a2 = a * cs.x - b * cs.y;
    float b2 = a * cs.y + b * cs.x;
    ptr[0] = f32_bf16(a2);
    ptr[1] = f32_bf16(b2);
  }
}

// -------------------------------------------------------------- rmsnorm ----
__global__ __launch_bounds__(256) void rmsnorm_kernel(
    const float* __restrict__ x, const float* __restrict__ wgt,
    unsigned short* __restrict__ out) {
  __shared__ float red[4];
  const int row = blockIdx.x;
  const int tid = threadIdx.x;
  const float* xr = x + (long)row * 2048 + tid * 8;
  const float4 v0 = *(const float4*)(xr);
  const float4 v1 = *(const float4*)(xr + 4);
  float ss = v0.x * v0.x + v0.y * v0.y + v0.z * v0.z + v0.w * v0.w +
             v1.x * v1.x + v1.y * v1.y + v1.z * v1.z + v1.w * v1.w;
#pragma unroll
  for (int off = 1; off < 64; off <<= 1) ss += __shfl_xor(ss, off);
  if ((tid & 63) == 0) red[tid >> 6] = ss;
  __syncthreads();
  float tot = red[0] + red[1] + red[2] + red[3];
  float sc = rsqrtf(tot * (1.0f / 2048.0f) + 1e-5f);
  const float4 w0 = *(const float4*)(wgt + tid * 8);
  const float4 w1 = *(const float4*)(wgt + tid * 8 + 4);
  ushort8 o;
  o[0] = f32_bf16(v0.x * sc * w0.x); o[1] = f32_bf16(v0.y * sc * w0.y);
  o[2] = f32_bf16(v0.z * sc * w0.z); o[3] = f32_bf16(v0.w * sc * w0.w);
  o[4] = f32_bf16(v1.x * sc * w1.x); o[5] = f32_bf16(v1.y * sc * w1.y);
  o[6] = f32_bf16(v1.z * sc * w1.z); o[7] = f32_bf16(v1.w * sc * w1.w);
  *(ushort8*)(out + (long)row * 2048 + tid * 8) = o;
}

// ------------------------------------------------- 3-deep pipelined gemm ----
// C[M,N] = A[M,K] @ B[N,K]^T, bf16 in, f32 acc. 256x128 tile, BK=64, 8 waves
// (2M x 4N, per-wave 128x32), THREE LDS buffers (144 KiB), XOR-swizzled.
// Prefetch tile t+2 during tile t; counted s_waitcnt vmcnt(6) at tile end
// (never a mid-loop drain -> loads get ~2 K-tiles of flight, T4).
// 2 phases per K-tile, each: 12 ds_read_b128 -> stage -> barrier ->
// lgkmcnt(0)+sched_barrier -> setprio(1) + 16 MFMA + setprio(0) -> barrier.
// EPI 0: store bf16. EPI 1: store f32 = res + acc. EPI 2: swiglu.
template <int EPI>
__global__ __launch_bounds__(512, 2) void gemm8p(
    const unsigned short* __restrict__ A, const unsigned short* __restrict__ B,
    void* __restrict__ Cout, const float* __restrict__ res, int M, int N, int K) {
  __shared__ __align__(16) unsigned short As[3][256 * 64];
  __shared__ __align__(16) unsigned short Bs[3][128 * 64];

  const int tid = threadIdx.x;
  const int lane = tid & 63;
  const int w = tid >> 6;
  const int c = lane & 15, g = lane >> 4;
  const int c7 = c & 7;
  const int wm = (w >> 2) * 128, wn = (w & 3) * 32;

  // bijective XCD swizzle (all grids have nwg % 8 == 0)
  const int id = blockIdx.y * gridDim.x + blockIdx.x;
  const int cpx = (gridDim.x * gridDim.y) >> 3;
  const int sid = (id & 7) * cpx + (id >> 3);
  const int bx = sid % gridDim.x;
  const int by = sid / gridDim.x;
  const long m0 = (long)bx * 256;
  const long n0 = (long)by * 128;

  const f32x4 fzero = {0.f, 0.f, 0.f, 0.f};
  f32x4 acc[8][2];
#pragma unroll
  for (int i = 0; i < 8; ++i)
#pragma unroll
    for (int j = 0; j < 2; ++j) acc[i][j] = fzero;

  auto stageA = [&](int buf, int k0) {  // 4 loads/thread
#pragma unroll
    for (int q = 0; q < 4; ++q) {
      int G = q * 512 + tid;
      int r = G >> 3;
      int cg = (G & 7) ^ (r & 7);
      async16(&As[buf][(q * 512 + (tid & ~63)) * 8],
              A + (m0 + r) * (long)K + k0 + cg * 8);
    }
  };
  auto stageB = [&](int buf, int k0) {  // 2 loads/thread
#pragma unroll
    for (int q = 0; q < 2; ++q) {
      int G = q * 512 + tid;
      int r = G >> 3;
      int cg = (G & 7) ^ (r & 7);
      async16(&Bs[buf][(q * 512 + (tid & ~63)) * 8],
              B + (n0 + r) * (long)K + k0 + cg * 8);
    }
  };

  const int NT = K >> 6;
  stageA(0, 0);
  stageB(0, 0);
  stageA(1, 64);
  stageB(1, 64);
  asm volatile("s_waitcnt vmcnt(6)" ::: "memory");  // tile 0 resident
  __builtin_amdgcn_s_barrier();

  const int swz0 = (g ^ c7) << 3;
  const int swz1 = ((4 + g) ^ c7) << 3;

  int cur = 0;
  for (int t = 0; t < NT; ++t) {
    const unsigned short* Ab = As[cur];
    const unsigned short* Bb = Bs[cur];
    const bool pf = (t + 2 < NT);
    const int nb = (cur >= 1) ? cur - 1 : 2;  // (cur+2)%3
#pragma unroll
    for (int ph = 0; ph < 2; ++ph) {
      bf16x8 af[4][2], bfr[2][2];
#pragma unroll
      for (int mf = 0; mf < 4; ++mf) {
        const int row = wm + ph * 64 + mf * 16 + c;
        af[mf][0] = *(const bf16x8*)(Ab + row * 64 + swz0);
        af[mf][1] = *(const bf16x8*)(Ab + row * 64 + swz1);
      }
#pragma unroll
      for (int nf = 0; nf < 2; ++nf) {
        const int row = wn + nf * 16 + c;
        bfr[nf][0] = *(const bf16x8*)(Bb + row * 64 + swz0);
        bfr[nf][1] = *(const bf16x8*)(Bb + row * 64 + swz1);
      }
      if (pf) {
        if (ph == 0) stageA(nb, (t + 2) << 6);
        else         stageB(nb, (t + 2) << 6);
      }
      __builtin_amdgcn_s_barrier();
      asm volatile("s_waitcnt lgkmcnt(0)" ::: "memory");
      __builtin_amdgcn_sched_barrier(0);
      __builtin_amdgcn_s_setprio(1);
#pragma unroll
      for (int kk = 0; kk < 2; ++kk)
#pragma unroll
        for (int mf = 0; mf < 4; ++mf)
#pragma unroll
          for (int nf = 0; nf < 2; ++nf)
            acc[ph * 4 + mf][nf] = __builtin_amdgcn_mfma_f32_16x16x32_bf16(
                af[mf][kk], bfr[nf][kk], acc[ph * 4 + mf][nf], 0, 0, 0);
      __builtin_amdgcn_s_setprio(0);
      if (ph == 1 && t + 1 < NT) {
        if (pf) asm volatile("s_waitcnt vmcnt(6)" ::: "memory");
        else    asm volatile("s_waitcnt vmcnt(0)" ::: "memory");
      }
      __builtin_amdgcn_s_barrier();
    }
    cur = (cur == 2) ? 0 : cur + 1;
  }

#pragma unroll
  for (int i = 0; i < 8; ++i) {
#pragma unroll
    for (int j = 0; j < 2; ++j) {
      const long row0 = m0 + wm + i * 16 + g * 4;
      const long col = n0 + wn + j * 16 + c;
#pragma unroll
      for (int r = 0; r < 4; ++r) {
        float v = acc[i][j][r];
        if (EPI == 0) {
          ((unsigned short*)Cout)[(row0 + r) * N + col] = f32_bf16(v);
        } else if (EPI == 1) {
          ((float*)Cout)[(row0 + r) * N + col] = res[(row0 + r) * N + col] + v;
        } else {
          float other = __shfl_xor(v, 1);
          if (!(c & 1)) {
            float sg = v / (1.0f + __expf(-v));
            ((unsigned short*)Cout)[(row0 + r) * (long)(N >> 1) + (col >> 1)] =
                f32_bf16(sg * other);
          }
        }
      }
    }
  }
}

// ----------------------------------------------------------- v transpose ----
__global__ __launch_bounds__(256) void transpose_v(
    const unsigned short* __restrict__ qkv, unsigned short* __restrict__ vT) {
  __shared__ __align__(16) unsigned short tile[64][72];
  const int tx = blockIdx.x;
  const int dx = blockIdx.y;
  const int tid = threadIdx.x;
  const int r = tid >> 3, cg = tid & 7;
#pragma unroll
  for (int it = 0; it < 2; ++it) {
    const unsigned short* src =
        qkv + (long)(tx * 64 + r + it * 32) * 3072 + 2560 + dx * 64 + cg * 8;
    *(ushort8*)(&tile[r + it * 32][cg * 8]) = *(const ushort8*)src;
  }
  __syncthreads();
#pragma unroll
  for (int it = 0; it < 2; ++it) {
    int d = r + it * 32;
    ushort8 v;
#pragma unroll
    for (int j = 0; j < 8; ++j) v[j] = tile[cg * 8 + j][d];
    *(ushort8*)(vT + (long)(dx * 64 + d) * 4096 + tx * 64 + cg * 8) = v;
  }
}

// ------------------------------------------------------------- attention ----
// Swapped-operand causal GQA flash attention (see round-1 notes).
__global__ __launch_bounds__(512, 2) void attn_kernel(
    const unsigned short* __restrict__ qkv, const unsigned short* __restrict__ vT,
    unsigned short* __restrict__ y) {
  constexpr float SCL = 0.08838834764831845f * 1.4426950408889634f;
  __shared__ __align__(16) unsigned short Kb[2][64 * 128];
  __shared__ __align__(16) unsigned short Vb[2][128 * 64];

  const int tid = threadIdx.x;
  const int lane = tid & 63;
  const int w = tid >> 6;
  const int c = lane & 15, g = lane >> 4;
  const int h = blockIdx.x >> 4;
  const int pid = blockIdx.x & 15;
  const int kvh = h >> 2;
  const int qt = (w < 4) ? pid : (31 - pid);
  const int q0w = qt * 128 + (w & 3) * 32;
  const int nsteps = 2 * (31 - pid) + 2;

  const f32x4 fzero = {0.f, 0.f, 0.f, 0.f};

  bf16x8 qf[2][4];
#pragma unroll
  for (int mt = 0; mt < 2; ++mt)
#pragma unroll
    for (int kk = 0; kk < 4; ++kk)
      qf[mt][kk] = *(const bf16x8*)(qkv + (long)(q0w + mt * 16 + c) * 3072 +
                                    h * 128 + kk * 32 + g * 8);

  f32x4 o[2][8];
#pragma unroll
  for (int mt = 0; mt < 2; ++mt)
#pragma unroll
    for (int dt = 0; dt < 8; ++dt) o[mt][dt] = fzero;
  float m[2] = {-1e30f, -1e30f}, l[2] = {0.f, 0.f};

  auto stage = [&](int buf, int kv0) {
#pragma unroll
    for (int k = 0; k < 2; ++k) {
      int G = k * 512 + tid;
      int row = G >> 4, colg = (G & 15) ^ (row & 7);
      async16(&Kb[buf][(k * 512 + (tid & ~63)) * 8],
              qkv + (long)(kv0 + row) * 3072 + 2048 + kvh * 128 + colg * 8);
    }
#pragma unroll
    for (int k = 0; k < 2; ++k) {
      int G = k * 512 + tid;
      int row = G >> 3, colg = (G & 7) ^ (row & 7);
      async16(&Vb[buf][(k * 512 + (tid & ~63)) * 8],
              vT + (long)(kvh * 128 + row) * 4096 + kv0 + colg * 8);
    }
  };

  stage(0, 0);
  for (int s = 0; s < nsteps; ++s) {
    const int kv0 = s * 64;
    const int bi = s & 1;
    if (s + 1 < nsteps) {
      stage(bi ^ 1, kv0 + 64);
      asm volatile("s_waitcnt vmcnt(4)" ::: "memory");
    } else {
      asm volatile("s_waitcnt vmcnt(0)" ::: "memory");
    }
    __builtin_amdgcn_s_barrier();
    if (kv0 <= q0w + 31) {
      const unsigned short* Ks = Kb[bi];
      const unsigned short* Vs = Vb[bi];
      f32x4 sv[2][4];
#pragma unroll
      for (int mt = 0; mt < 2; ++mt)
#pragma unroll
        for (int nt = 0; nt < 4; ++nt) sv[mt][nt] = fzero;
#pragma unroll
      for (int kk = 0; kk < 4; ++kk) {
        bf16x8 kf[4];
#pragma unroll
        for (int nt = 0; nt < 4; ++nt)
          kf[nt] = *(const bf16x8*)(Ks + (nt * 16 + c) * 128 +
                                    (((kk * 4 + g) ^ (c & 7)) << 3));
#pragma unroll
        for (int mt = 0; mt < 2; ++mt)
#pragma unroll
          for (int nt = 0; nt < 4; ++nt)
            sv[mt][nt] = __builtin_amdgcn_mfma_f32_16x16x32_bf16(
                kf[nt], qf[mt][kk], sv[mt][nt], 0, 0, 0);
      }
      const bool need_mask = (kv0 + 63 > q0w);
      float al[2];
#pragma unroll
      for (int mt = 0; mt < 2; ++mt) {
        const int qrow = q0w + mt * 16 + c;
#pragma unroll
        for (int nt = 0; nt < 4; ++nt)
#pragma unroll
          for (int r = 0; r < 4; ++r) {
            float xx = sv[mt][nt][r] * SCL;
            if (need_mask && (kv0 + nt * 16 + g * 4 + r > qrow)) xx = -3.0e38f;
            sv[mt][nt][r] = xx;
          }
        float mx = -3.0e38f;
#pragma unroll
        for (int nt = 0; nt < 4; ++nt)
#pragma unroll
          for (int r = 0; r < 4; ++r) mx = fmaxf(mx, sv[mt][nt][r]);
        mx = fmaxf(mx, __shfl_xor(mx, 16));
        mx = fmaxf(mx, __shfl_xor(mx, 32));
        const float mn = fmaxf(m[mt], mx);
        const float a = exp2f(m[mt] - mn);
        m[mt] = mn;
        al[mt] = a;
        float rs = 0.f;
#pragma unroll
        for (int nt = 0; nt < 4; ++nt)
#pragma unroll
          for (int r = 0; r < 4; ++r) {
            float p = exp2f(sv[mt][nt][r] - mn);
            sv[mt][nt][r] = p;
            rs += p;
          }
        rs += __shfl_xor(rs, 16);
        rs += __shfl_xor(rs, 32);
        l[mt] = l[mt] * a + rs;
#pragma unroll
        for (int dt = 0; dt < 8; ++dt) o[mt][dt] *= al[mt];
      }
#pragma unroll
      for (int nt = 0; nt < 4; ++nt) {
        bf16x4 pb[2];
#pragma unroll
        for (int mt = 0; mt < 2; ++mt) {
          int lo_, hi_;
          float s0 = sv[mt][nt][0], s1 = sv[mt][nt][1];
          float s2 = sv[mt][nt][2], s3 = sv[mt][nt][3];
          asm("v_cvt_pk_bf16_f32 %0, %1, %2" : "=v"(lo_) : "v"(s0), "v"(s1));
          asm("v_cvt_pk_bf16_f32 %0, %1, %2" : "=v"(hi_) : "v"(s2), "v"(s3));
          int2 pk = make_int2(lo_, hi_);
          pb[mt] = __builtin_bit_cast(bf16x4, pk);
        }
#pragma unroll
        for (int dt = 0; dt < 8; ++dt) {
          bf16x4 vt = *(const bf16x4*)(Vs + (dt * 16 + c) * 64 +
                                       (((nt * 2 + (g >> 1)) ^ (c & 7)) << 3) +
                                       (g & 1) * 4);
          o[0][dt] = mfma16(vt, pb[0], o[0][dt]);
          o[1][dt] = mfma16(vt, pb[1], o[1][dt]);
        }
      }
    }
    __builtin_amdgcn_s_barrier();
  }
#pragma unroll
  for (int mt = 0; mt < 2; ++mt) {
    const float inv = 1.0f / l[mt];
    const long qrow = q0w + mt * 16 + c;
#pragma unroll
    for (int dt = 0; dt < 8; ++dt) {
      us4 st;
      st[0] = f32_bf16(o[mt][dt][0] * inv);
      st[1] = f32_bf16(o[mt][dt][1] * inv);
      st[2] = f32_bf16(o[mt][dt][2] * inv);
      st[3] = f32_bf16(o[mt][dt][3] * inv);
      *(us4*)(y + qrow * 2048 + h * 128 + dt * 16 + g * 4) = st;
    }
  }
}

// ------------------------------------------------------------------ host ----
extern "C" void kernel_launch(void* const* d_in, const int* in_sizes, int n_in,
                              void* d_out, int out_size, void* d_ws, size_t ws_size,
                              hipStream_t stream) {
  (void)in_sizes; (void)n_in; (void)out_size; (void)ws_size;
  const float* x      = (const float*)d_in[0];
  const float* attn_w = (const float*)d_in[2];
  const float* wq     = (const float*)d_in[3];
  const float* wk     = (const float*)d_in[4];
  const float* wv     = (const float*)d_in[5];
  const float* wo     = (const float*)d_in[6];
  const float* ffn_w  = (const float*)d_in[7];
  const float* wg     = (const float*)d_in[8];
  const float* wu     = (const float*)d_in[9];
  const float* wd     = (const float*)d_in[10];
  float* out = (float*)d_out;

  char* ws = (char*)d_ws;
  size_t off = 0;
  auto alloc = [&](size_t bytes) {
    char* p = ws + off;
    off += (bytes + 255) & ~(size_t)255;
    return p;
  };
  float2* rope_tab        = (float2*)alloc(4096UL * 64 * sizeof(float2));
  unsigned short* wqkv_b  = (unsigned short*)alloc(3072UL * 2048 * 2);
  unsigned short* wo_b    = (unsigned short*)alloc(2048UL * 2048 * 2);
  unsigned short* wgu_b   = (unsigned short*)alloc(16384UL * 2048 * 2);
  unsigned short* wd_b    = (unsigned short*)alloc(2048UL * 8192 * 2);
  unsigned short* h_b     = (unsigned short*)alloc(4096UL * 2048 * 2);
  unsigned short* qkv_b   = (unsigned short*)alloc(4096UL * 3072 * 2);
  unsigned short* vT_b    = (unsigned short*)alloc(512UL * 4096 * 2);
  unsigned short* y_b     = (unsigned short*)alloc(4096UL * 2048 * 2);
  float* r1               = (float*)alloc(4096UL * 2048 * 4);
  unsigned short* t_b     = (unsigned short*)alloc(4096UL * 8192 * 2);

  // weight casts
  cast_bf16_kernel<<<2048, 256, 0, stream>>>(wq, wqkv_b, 524288);
  cast_bf16_kernel<<<512, 256, 0, stream>>>(wk, wqkv_b + 2048L * 2048, 131072);
  cast_bf16_kernel<<<512, 256, 0, stream>>>(wv, wqkv_b + 2560L * 2048, 131072);
  cast_bf16_kernel<<<2048, 256, 0, stream>>>(wo, wo_b, 524288);
  cast_gu_kernel<<<16384, 256, 0, stream>>>(wg, wu, wgu_b);
  cast_bf16_kernel<<<8192, 256, 0, stream>>>(wd, wd_b, 2097152);
  rope_table_kernel<<<1024, 256, 0, stream>>>(rope_tab);

  // attn branch
  rmsnorm_kernel<<<4096, 256, 0, stream>>>(x, attn_w, h_b);
  {
    dim3 grid(16, 24);
    gemm8p<0><<<grid, 512, 0, stream>>>(h_b, wqkv_b, qkv_b, nullptr, 4096, 3072, 2048);
  }
  rope_apply_kernel<<<4096, 256, 0, stream>>>(qkv_b, rope_tab);
  {
    dim3 grid(64, 8);
    transpose_v<<<grid, 256, 0, stream>>>(qkv_b, vT_b);
  }
  attn_kernel<<<256, 512, 0, stream>>>(qkv_b, vT_b, y_b);
  {
    dim3 grid(16, 16);
    gemm8p<1><<<grid, 512, 0, stream>>>(y_b, wo_b, r1, x, 4096, 2048, 2048);
  }

  // ffn branch
  rmsnorm_kernel<<<4096, 256, 0, stream>>>(r1, ffn_w, h_b);
  {
    dim3 grid(16, 128);
    gemm8p<2><<<grid, 512, 0, stream>>>(h_b, wgu_b, t_b, nullptr, 4096, 16384, 2048);
  }
  {
    dim3 grid(16, 16);
    gemm8p<1><<<grid, 512, 0, stream>>>(t_b, wd_b, out, r1, 4096, 2048, 8192);
  }
}

// Round 5
// 899.691 us; speedup vs baseline: 1.6135x; 1.0632x over previous
//
#include <hip/hip_runtime.h>
#include <math.h>

#define DEVI static __device__ __forceinline__

typedef __attribute__((ext_vector_type(8))) short bf16x8;
typedef __attribute__((ext_vector_type(4))) short bf16x4;
typedef __attribute__((ext_vector_type(8))) unsigned short ushort8;
typedef __attribute__((ext_vector_type(4))) unsigned short us4;
typedef __attribute__((ext_vector_type(4))) float f32x4;

DEVI unsigned short f32_bf16(float f) {
  unsigned int u = __float_as_uint(f);
  u += 0x7fffu + ((u >> 16) & 1u);
  return (unsigned short)(u >> 16);
}
DEVI float bf16_f32(unsigned short h) {
  return __uint_as_float(((unsigned int)h) << 16);
}

DEVI void async16(void* lds, const void* g) {
  __builtin_amdgcn_global_load_lds(
      (const __attribute__((address_space(1))) void*)g,
      (__attribute__((address_space(3))) void*)lds,
      16, 0, 0);
}

#if __has_builtin(__builtin_amdgcn_mfma_f32_16x16x16bf16_1k)
DEVI f32x4 mfma16(bf16x4 a, bf16x4 b, f32x4 c) {
  return __builtin_amdgcn_mfma_f32_16x16x16bf16_1k(a, b, c, 0, 0, 0);
}
#else
DEVI f32x4 mfma16(bf16x4 a, bf16x4 b, f32x4 c) {
  asm volatile("v_mfma_f32_16x16x16_bf16 %0, %1, %2, %0" : "+v"(c) : "v"(a), "v"(b));
  return c;
}
#endif

// ---------------------------------------------------------------- casts ----
__global__ __launch_bounds__(256) void cast_bf16_kernel(
    const float* __restrict__ src, unsigned short* __restrict__ dst, long n8) {
  long i = (long)blockIdx.x * 256 + threadIdx.x;
  if (i >= n8) return;
  const float4 a = *(const float4*)(src + i * 8);
  const float4 b = *(const float4*)(src + i * 8 + 4);
  ushort8 o;
  o[0] = f32_bf16(a.x); o[1] = f32_bf16(a.y); o[2] = f32_bf16(a.z); o[3] = f32_bf16(a.w);
  o[4] = f32_bf16(b.x); o[5] = f32_bf16(b.y); o[6] = f32_bf16(b.z); o[7] = f32_bf16(b.w);
  *(ushort8*)(dst + i * 8) = o;
}

// gate/up interleave: dst row 2j = gate j, row 2j+1 = up j.  [16384][2048]
__global__ __launch_bounds__(256) void cast_gu_kernel(
    const float* __restrict__ gate, const float* __restrict__ up,
    unsigned short* __restrict__ dst) {
  long i = (long)blockIdx.x * 256 + threadIdx.x;
  long row = i >> 8;
  long col = (i & 255) * 8;
  const float* src = ((row & 1) ? up : gate) + ((row >> 1) << 11) + col;
  const float4 a = *(const float4*)(src);
  const float4 b = *(const float4*)(src + 4);
  ushort8 o;
  o[0] = f32_bf16(a.x); o[1] = f32_bf16(a.y); o[2] = f32_bf16(a.z); o[3] = f32_bf16(a.w);
  o[4] = f32_bf16(b.x); o[5] = f32_bf16(b.y); o[6] = f32_bf16(b.z); o[7] = f32_bf16(b.w);
  *(ushort8*)(dst + i * 8) = o;
}

// ----------------------------------------------------------------- rope ----
__global__ __launch_bounds__(256) void rope_table_kernel(float2* __restrict__ tab) {
  int idx = blockIdx.x * 256 + threadIdx.x;
  int t = idx >> 6, i = idx & 63;
  float inv = __expf(-(float)(2 * i) * (1.0f / 128.0f) * 13.122363377404328f);
  float f = (float)t * inv;
  tab[idx] = make_float2(cosf(f), sinf(f));
}

__global__ __launch_bounds__(256) void rope_apply_kernel(
    unsigned short* __restrict__ qkv, const float2* __restrict__ tab) {
  const int row = blockIdx.x;
  const int tid = threadIdx.x;
#pragma unroll
  for (int it = 0; it < 5; ++it) {
    int p = tid + it * 256;
    int head = p >> 6, i = p & 63;
    int col = (p < 1024) ? (head * 128 + 2 * i) : (2048 + (head - 16) * 128 + 2 * i);
    unsigned short* ptr = qkv + (long)row * 3072 + col;
    float a = bf16_f32(ptr[0]), b = bf16_f32(ptr[1]);
    float2 cs = tab[row * 64 + i];
    float a2 = a * cs.x - b * cs.y;
    float b2 = a * cs.y + b * cs.x;
    ptr[0] = f32_bf16(a2);
    ptr[1] = f32_bf16(b2);
  }
}

// -------------------------------------------------------------- rmsnorm ----
__global__ __launch_bounds__(256) void rmsnorm_kernel(
    const float* __restrict__ x, const float* __restrict__ wgt,
    unsigned short* __restrict__ out) {
  __shared__ float red[4];
  const int row = blockIdx.x;
  const int tid = threadIdx.x;
  const float* xr = x + (long)row * 2048 + tid * 8;
  const float4 v0 = *(const float4*)(xr);
  const float4 v1 = *(const float4*)(xr + 4);
  float ss = v0.x * v0.x + v0.y * v0.y + v0.z * v0.z + v0.w * v0.w +
             v1.x * v1.x + v1.y * v1.y + v1.z * v1.z + v1.w * v1.w;
#pragma unroll
  for (int off = 1; off < 64; off <<= 1) ss += __shfl_xor(ss, off);
  if ((tid & 63) == 0) red[tid >> 6] = ss;
  __syncthreads();
  float tot = red[0] + red[1] + red[2] + red[3];
  float sc = rsqrtf(tot * (1.0f / 2048.0f) + 1e-5f);
  const float4 w0 = *(const float4*)(wgt + tid * 8);
  const float4 w1 = *(const float4*)(wgt + tid * 8 + 4);
  ushort8 o;
  o[0] = f32_bf16(v0.x * sc * w0.x); o[1] = f32_bf16(v0.y * sc * w0.y);
  o[2] = f32_bf16(v0.z * sc * w0.z); o[3] = f32_bf16(v0.w * sc * w0.w);
  o[4] = f32_bf16(v1.x * sc * w1.x); o[5] = f32_bf16(v1.y * sc * w1.y);
  o[6] = f32_bf16(v1.z * sc * w1.z); o[7] = f32_bf16(v1.w * sc * w1.w);
  *(ushort8*)(out + (long)row * 2048 + tid * 8) = o;
}

// --------------------------------------------- BK=32 4-buffer gemm ----
// C[M,N] = A[M,K] @ B[N,K]^T, bf16 in, f32 acc.
// BN=256: 256x256 tile, waves 2Mx4N, per-wave 128x64 (42.7 FLOP/LDS-byte).
// BN=128: 256x128 tile, waves 4Mx2N, per-wave 64x64  (32 FLOP/LDS-byte).
// BK=32, FOUR LDS buffers; prefetch tile t+2 during t; tile-end wait
// vmcnt(VMN) keeps t+2's loads in flight (~1 K-tile ~1200cyc > HBM lat).
// [rows][32] LDS tiles: fragment reads (row=base+c, granule=g) hit all 8
// bank-groups uniformly -> conflict-free WITHOUT swizzle; staging linear.
// One barrier per K-tile. EPI 0: bf16. EPI 1: f32 = res+acc. EPI 2: swiglu.
template <int BN, int EPI>
__global__ __launch_bounds__(512, 2) void gemm_p(
    const unsigned short* __restrict__ A, const unsigned short* __restrict__ B,
    void* __restrict__ Cout, const float* __restrict__ res, int M, int N, int K) {
  constexpr int MH = (BN == 256) ? 2 : 1;   // m-half phases per tile
  constexpr int MF = MH * 4;                 // m-fragments per wave
  constexpr int BL = (BN == 256) ? 2 : 1;    // B loads/thread/tile
  __shared__ __align__(16) unsigned short As[4][256 * 32];
  __shared__ __align__(16) unsigned short Bs[4][BN * 32];

  const int tid = threadIdx.x;
  const int lane = tid & 63;
  const int w = tid >> 6;
  const int c = lane & 15, g = lane >> 4;
  const int wm = (BN == 256) ? (w >> 2) * 128 : (w >> 1) * 64;
  const int wn = (BN == 256) ? (w & 3) * 64 : (w & 1) * 64;

  // bijective XCD swizzle (all grids have nwg % 8 == 0)
  const int id = blockIdx.y * gridDim.x + blockIdx.x;
  const int cpx = (gridDim.x * gridDim.y) >> 3;
  const int sid = (id & 7) * cpx + (id >> 3);
  const int bx = sid % gridDim.x;
  const int by = sid / gridDim.x;
  const long m0 = (long)bx * 256;
  const long n0 = (long)by * BN;

  const f32x4 fzero = {0.f, 0.f, 0.f, 0.f};
  f32x4 acc[MF][4];
#pragma unroll
  for (int i = 0; i < MF; ++i)
#pragma unroll
    for (int j = 0; j < 4; ++j) acc[i][j] = fzero;

  auto stageA = [&](int buf, int k0) {  // 2 loads/thread (1024 granules)
#pragma unroll
    for (int q = 0; q < 2; ++q) {
      int G = q * 512 + tid;
      async16(&As[buf][(q * 512 + (tid & ~63)) * 8],
              A + (m0 + (G >> 2)) * (long)K + k0 + (G & 3) * 8);
    }
  };
  auto stageB = [&](int buf, int k0) {
#pragma unroll
    for (int q = 0; q < BL; ++q) {
      int G = q * 512 + tid;
      async16(&Bs[buf][(q * 512 + (tid & ~63)) * 8],
              B + (n0 + (G >> 2)) * (long)K + k0 + (G & 3) * 8);
    }
  };

  const int NT = K >> 5;
  stageA(0, 0);
  stageB(0, 0);
  stageA(1, 32);
  stageB(1, 32);
  if constexpr (BN == 256)
    asm volatile("s_waitcnt vmcnt(4)" ::: "memory");
  else
    asm volatile("s_waitcnt vmcnt(3)" ::: "memory");
  __builtin_amdgcn_s_barrier();

  for (int t = 0; t < NT; ++t) {
    const int buf = t & 3;
    const unsigned short* Ab = As[buf];
    const unsigned short* Bb = Bs[buf];
    const bool pf = (t + 2 < NT);
    const int nb = (t + 2) & 3;

    bf16x8 bfr[4];
#pragma unroll
    for (int nf = 0; nf < 4; ++nf)
      bfr[nf] = *(const bf16x8*)(Bb + (wn + nf * 16 + c) * 32 + g * 8);

#pragma unroll
    for (int mh = 0; mh < MH; ++mh) {
      bf16x8 af[4];
#pragma unroll
      for (int mf = 0; mf < 4; ++mf)
        af[mf] = *(const bf16x8*)(Ab + (wm + mh * 64 + mf * 16 + c) * 32 + g * 8);
      if (pf) {
        if (mh == 0) stageA(nb, (t + 2) << 5);
        if (mh == MH - 1) stageB(nb, (t + 2) << 5);
      }
      __builtin_amdgcn_sched_barrier(0);
      __builtin_amdgcn_s_setprio(1);
#pragma unroll
      for (int mf = 0; mf < 4; ++mf)
#pragma unroll
        for (int nf = 0; nf < 4; ++nf)
          acc[mh * 4 + mf][nf] = __builtin_amdgcn_mfma_f32_16x16x32_bf16(
              af[mf], bfr[nf], acc[mh * 4 + mf][nf], 0, 0, 0);
      __builtin_amdgcn_s_setprio(0);
    }

    if (pf) {
      if constexpr (BN == 256)
        asm volatile("s_waitcnt vmcnt(4)" ::: "memory");
      else
        asm volatile("s_waitcnt vmcnt(3)" ::: "memory");
    } else {
      asm volatile("s_waitcnt vmcnt(0)" ::: "memory");
    }
    __builtin_amdgcn_s_barrier();
  }

#pragma unroll
  for (int i = 0; i < MF; ++i) {
#pragma unroll
    for (int j = 0; j < 4; ++j) {
      const long row0 = m0 + wm + i * 16 + g * 4;
      const long col = n0 + wn + j * 16 + c;
#pragma unroll
      for (int r = 0; r < 4; ++r) {
        float v = acc[i][j][r];
        if (EPI == 0) {
          ((unsigned short*)Cout)[(row0 + r) * N + col] = f32_bf16(v);
        } else if (EPI == 1) {
          ((float*)Cout)[(row0 + r) * N + col] = res[(row0 + r) * N + col] + v;
        } else {
          float other = __shfl_xor(v, 1);
          if (!(c & 1)) {
            float sg = v / (1.0f + __expf(-v));
            ((unsigned short*)Cout)[(row0 + r) * (long)(N >> 1) + (col >> 1)] =
                f32_bf16(sg * other);
          }
        }
      }
    }
  }
}

// ----------------------------------------------------------- v transpose ----
__global__ __launch_bounds__(256) void transpose_v(
    const unsigned short* __restrict__ qkv, unsigned short* __restrict__ vT) {
  __shared__ __align__(16) unsigned short tile[64][72];
  const int tx = blockIdx.x;
  const int dx = blockIdx.y;
  const int tid = threadIdx.x;
  const int r = tid >> 3, cg = tid & 7;
#pragma unroll
  for (int it = 0; it < 2; ++it) {
    const unsigned short* src =
        qkv + (long)(tx * 64 + r + it * 32) * 3072 + 2560 + dx * 64 + cg * 8;
    *(ushort8*)(&tile[r + it * 32][cg * 8]) = *(const ushort8*)src;
  }
  __syncthreads();
#pragma unroll
  for (int it = 0; it < 2; ++it) {
    int d = r + it * 32;
    ushort8 v;
#pragma unroll
    for (int j = 0; j < 8; ++j) v[j] = tile[cg * 8 + j][d];
    *(ushort8*)(vT + (long)(dx * 64 + d) * 4096 + tx * 64 + cg * 8) = v;
  }
}

// ------------------------------------------------------------- attention ----
// Swapped-operand causal GQA flash attention (see round-1 notes).
__global__ __launch_bounds__(512, 2) void attn_kernel(
    const unsigned short* __restrict__ qkv, const unsigned short* __restrict__ vT,
    unsigned short* __restrict__ y) {
  constexpr float SCL = 0.08838834764831845f * 1.4426950408889634f;
  __shared__ __align__(16) unsigned short Kb[2][64 * 128];
  __shared__ __align__(16) unsigned short Vb[2][128 * 64];

  const int tid = threadIdx.x;
  const int lane = tid & 63;
  const int w = tid >> 6;
  const int c = lane & 15, g = lane >> 4;
  const int h = blockIdx.x >> 4;
  const int pid = blockIdx.x & 15;
  const int kvh = h >> 2;
  const int qt = (w < 4) ? pid : (31 - pid);
  const int q0w = qt * 128 + (w & 3) * 32;
  const int nsteps = 2 * (31 - pid) + 2;

  const f32x4 fzero = {0.f, 0.f, 0.f, 0.f};

  bf16x8 qf[2][4];
#pragma unroll
  for (int mt = 0; mt < 2; ++mt)
#pragma unroll
    for (int kk = 0; kk < 4; ++kk)
      qf[mt][kk] = *(const bf16x8*)(qkv + (long)(q0w + mt * 16 + c) * 3072 +
                                    h * 128 + kk * 32 + g * 8);

  f32x4 o[2][8];
#pragma unroll
  for (int mt = 0; mt < 2; ++mt)
#pragma unroll
    for (int dt = 0; dt < 8; ++dt) o[mt][dt] = fzero;
  float m[2] = {-1e30f, -1e30f}, l[2] = {0.f, 0.f};

  auto stage = [&](int buf, int kv0) {
#pragma unroll
    for (int k = 0; k < 2; ++k) {
      int G = k * 512 + tid;
      int row = G >> 4, colg = (G & 15) ^ (row & 7);
      async16(&Kb[buf][(k * 512 + (tid & ~63)) * 8],
              qkv + (long)(kv0 + row) * 3072 + 2048 + kvh * 128 + colg * 8);
    }
#pragma unroll
    for (int k = 0; k < 2; ++k) {
      int G = k * 512 + tid;
      int row = G >> 3, colg = (G & 7) ^ (row & 7);
      async16(&Vb[buf][(k * 512 + (tid & ~63)) * 8],
              vT + (long)(kvh * 128 + row) * 4096 + kv0 + colg * 8);
    }
  };

  stage(0, 0);
  for (int s = 0; s < nsteps; ++s) {
    const int kv0 = s * 64;
    const int bi = s & 1;
    if (s + 1 < nsteps) {
      stage(bi ^ 1, kv0 + 64);
      asm volatile("s_waitcnt vmcnt(4)" ::: "memory");
    } else {
      asm volatile("s_waitcnt vmcnt(0)" ::: "memory");
    }
    __builtin_amdgcn_s_barrier();
    if (kv0 <= q0w + 31) {
      const unsigned short* Ks = Kb[bi];
      const unsigned short* Vs = Vb[bi];
      f32x4 sv[2][4];
#pragma unroll
      for (int mt = 0; mt < 2; ++mt)
#pragma unroll
        for (int nt = 0; nt < 4; ++nt) sv[mt][nt] = fzero;
#pragma unroll
      for (int kk = 0; kk < 4; ++kk) {
        bf16x8 kf[4];
#pragma unroll
        for (int nt = 0; nt < 4; ++nt)
          kf[nt] = *(const bf16x8*)(Ks + (nt * 16 + c) * 128 +
                                    (((kk * 4 + g) ^ (c & 7)) << 3));
#pragma unroll
        for (int mt = 0; mt < 2; ++mt)
#pragma unroll
          for (int nt = 0; nt < 4; ++nt)
            sv[mt][nt] = __builtin_amdgcn_mfma_f32_16x16x32_bf16(
                kf[nt], qf[mt][kk], sv[mt][nt], 0, 0, 0);
      }
      const bool need_mask = (kv0 + 63 > q0w);
      float al[2];
#pragma unroll
      for (int mt = 0; mt < 2; ++mt) {
        const int qrow = q0w + mt * 16 + c;
#pragma unroll
        for (int nt = 0; nt < 4; ++nt)
#pragma unroll
          for (int r = 0; r < 4; ++r) {
            float xx = sv[mt][nt][r] * SCL;
            if (need_mask && (kv0 + nt * 16 + g * 4 + r > qrow)) xx = -3.0e38f;
            sv[mt][nt][r] = xx;
          }
        float mx = -3.0e38f;
#pragma unroll
        for (int nt = 0; nt < 4; ++nt)
#pragma unroll
          for (int r = 0; r < 4; ++r) mx = fmaxf(mx, sv[mt][nt][r]);
        mx = fmaxf(mx, __shfl_xor(mx, 16));
        mx = fmaxf(mx, __shfl_xor(mx, 32));
        const float mn = fmaxf(m[mt], mx);
        const float a = exp2f(m[mt] - mn);
        m[mt] = mn;
        al[mt] = a;
        float rs = 0.f;
#pragma unroll
        for (int nt = 0; nt < 4; ++nt)
#pragma unroll
          for (int r = 0; r < 4; ++r) {
            float p = exp2f(sv[mt][nt][r] - mn);
            sv[mt][nt][r] = p;
            rs += p;
          }
        rs += __shfl_xor(rs, 16);
        rs += __shfl_xor(rs, 32);
        l[mt] = l[mt] * a + rs;
#pragma unroll
        for (int dt = 0; dt < 8; ++dt) o[mt][dt] *= al[mt];
      }
#pragma unroll
      for (int nt = 0; nt < 4; ++nt) {
        bf16x4 pb[2];
#pragma unroll
        for (int mt = 0; mt < 2; ++mt) {
          int lo_, hi_;
          float s0 = sv[mt][nt][0], s1 = sv[mt][nt][1];
          float s2 = sv[mt][nt][2], s3 = sv[mt][nt][3];
          asm("v_cvt_pk_bf16_f32 %0, %1, %2" : "=v"(lo_) : "v"(s0), "v"(s1));
          asm("v_cvt_pk_bf16_f32 %0, %1, %2" : "=v"(hi_) : "v"(s2), "v"(s3));
          int2 pk = make_int2(lo_, hi_);
          pb[mt] = __builtin_bit_cast(bf16x4, pk);
        }
#pragma unroll
        for (int dt = 0; dt < 8; ++dt) {
          bf16x4 vt = *(const bf16x4*)(Vs + (dt * 16 + c) * 64 +
                                       (((nt * 2 + (g >> 1)) ^ (c & 7)) << 3) +
                                       (g & 1) * 4);
          o[0][dt] = mfma16(vt, pb[0], o[0][dt]);
          o[1][dt] = mfma16(vt, pb[1], o[1][dt]);
        }
      }
    }
    __builtin_amdgcn_s_barrier();
  }
#pragma unroll
  for (int mt = 0; mt < 2; ++mt) {
    const float inv = 1.0f / l[mt];
    const long qrow = q0w + mt * 16 + c;
#pragma unroll
    for (int dt = 0; dt < 8; ++dt) {
      us4 st;
      st[0] = f32_bf16(o[mt][dt][0] * inv);
      st[1] = f32_bf16(o[mt][dt][1] * inv);
      st[2] = f32_bf16(o[mt][dt][2] * inv);
      st[3] = f32_bf16(o[mt][dt][3] * inv);
      *(us4*)(y + qrow * 2048 + h * 128 + dt * 16 + g * 4) = st;
    }
  }
}

// ------------------------------------------------------------------ host ----
extern "C" void kernel_launch(void* const* d_in, const int* in_sizes, int n_in,
                              void* d_out, int out_size, void* d_ws, size_t ws_size,
                              hipStream_t stream) {
  (void)in_sizes; (void)n_in; (void)out_size; (void)ws_size;
  const float* x      = (const float*)d_in[0];
  const float* attn_w = (const float*)d_in[2];
  const float* wq     = (const float*)d_in[3];
  const float* wk     = (const float*)d_in[4];
  const float* wv     = (const float*)d_in[5];
  const float* wo     = (const float*)d_in[6];
  const float* ffn_w  = (const float*)d_in[7];
  const float* wg     = (const float*)d_in[8];
  const float* wu     = (const float*)d_in[9];
  const float* wd     = (const float*)d_in[10];
  float* out = (float*)d_out;

  char* ws = (char*)d_ws;
  size_t off = 0;
  auto alloc = [&](size_t bytes) {
    char* p = ws + off;
    off += (bytes + 255) & ~(size_t)255;
    return p;
  };
  float2* rope_tab        = (float2*)alloc(4096UL * 64 * sizeof(float2));
  unsigned short* wqkv_b  = (unsigned short*)alloc(3072UL * 2048 * 2);
  unsigned short* wo_b    = (unsigned short*)alloc(2048UL * 2048 * 2);
  unsigned short* wgu_b   = (unsigned short*)alloc(16384UL * 2048 * 2);
  unsigned short* wd_b    = (unsigned short*)alloc(2048UL * 8192 * 2);
  unsigned short* h_b     = (unsigned short*)alloc(4096UL * 2048 * 2);
  unsigned short* qkv_b   = (unsigned short*)alloc(4096UL * 3072 * 2);
  unsigned short* vT_b    = (unsigned short*)alloc(512UL * 4096 * 2);
  unsigned short* y_b     = (unsigned short*)alloc(4096UL * 2048 * 2);
  float* r1               = (float*)alloc(4096UL * 2048 * 4);
  unsigned short* t_b     = (unsigned short*)alloc(4096UL * 8192 * 2);

  // weight casts
  cast_bf16_kernel<<<2048, 256, 0, stream>>>(wq, wqkv_b, 524288);
  cast_bf16_kernel<<<512, 256, 0, stream>>>(wk, wqkv_b + 2048L * 2048, 131072);
  cast_bf16_kernel<<<512, 256, 0, stream>>>(wv, wqkv_b + 2560L * 2048, 131072);
  cast_bf16_kernel<<<2048, 256, 0, stream>>>(wo, wo_b, 524288);
  cast_gu_kernel<<<16384, 256, 0, stream>>>(wg, wu, wgu_b);
  cast_bf16_kernel<<<8192, 256, 0, stream>>>(wd, wd_b, 2097152);
  rope_table_kernel<<<1024, 256, 0, stream>>>(rope_tab);

  // attn branch
  rmsnorm_kernel<<<4096, 256, 0, stream>>>(x, attn_w, h_b);
  {
    dim3 grid(16, 12);
    gemm_p<256, 0><<<grid, 512, 0, stream>>>(h_b, wqkv_b, qkv_b, nullptr, 4096, 3072, 2048);
  }
  rope_apply_kernel<<<4096, 256, 0, stream>>>(qkv_b, rope_tab);
  {
    dim3 grid(64, 8);
    transpose_v<<<grid, 256, 0, stream>>>(qkv_b, vT_b);
  }
  attn_kernel<<<256, 512, 0, stream>>>(qkv_b, vT_b, y_b);
  {
    dim3 grid(16, 16);
    gemm_p<128, 1><<<grid, 512, 0, stream>>>(y_b, wo_b, r1, x, 4096, 2048, 2048);
  }

  // ffn branch
  rmsnorm_kernel<<<4096, 256, 0, stream>>>(r1, ffn_w, h_b);
  {
    dim3 grid(16, 64);
    gemm_p<256, 2><<<grid, 512, 0, stream>>>(h_b, wgu_b, t_b, nullptr, 4096, 16384, 2048);
  }
  {
    dim3 grid(16, 16);
    gemm_p<128, 1><<<grid, 512, 0, stream>>>(t_b, wd_b, out, r1, 4096, 2048, 8192);
  }
}

// Round 6
// 887.309 us; speedup vs baseline: 1.6360x; 1.0140x over previous
//
#include <hip/hip_runtime.h>
#include <math.h>

#define DEVI static __device__ __forceinline__

typedef __attribute__((ext_vector_type(8))) short bf16x8;
typedef __attribute__((ext_vector_type(4))) short bf16x4;
typedef __attribute__((ext_vector_type(8))) unsigned short ushort8;
typedef __attribute__((ext_vector_type(4))) unsigned short us4;
typedef __attribute__((ext_vector_type(4))) float f32x4;

DEVI unsigned short f32_bf16(float f) {
  unsigned int u = __float_as_uint(f);
  u += 0x7fffu + ((u >> 16) & 1u);
  return (unsigned short)(u >> 16);
}
DEVI float bf16_f32(unsigned short h) {
  return __uint_as_float(((unsigned int)h) << 16);
}

DEVI void async16(void* lds, const void* g) {
  __builtin_amdgcn_global_load_lds(
      (const __attribute__((address_space(1))) void*)g,
      (__attribute__((address_space(3))) void*)lds,
      16, 0, 0);
}

#if __has_builtin(__builtin_amdgcn_mfma_f32_16x16x16bf16_1k)
DEVI f32x4 mfma16(bf16x4 a, bf16x4 b, f32x4 c) {
  return __builtin_amdgcn_mfma_f32_16x16x16bf16_1k(a, b, c, 0, 0, 0);
}
#else
DEVI f32x4 mfma16(bf16x4 a, bf16x4 b, f32x4 c) {
  asm volatile("v_mfma_f32_16x16x16_bf16 %0, %1, %2, %0" : "+v"(c) : "v"(a), "v"(b));
  return c;
}
#endif

// ---------------------------------------------------------------- casts ----
__global__ __launch_bounds__(256) void cast_bf16_kernel(
    const float* __restrict__ src, unsigned short* __restrict__ dst, long n8) {
  long i = (long)blockIdx.x * 256 + threadIdx.x;
  if (i >= n8) return;
  const float4 a = *(const float4*)(src + i * 8);
  const float4 b = *(const float4*)(src + i * 8 + 4);
  ushort8 o;
  o[0] = f32_bf16(a.x); o[1] = f32_bf16(a.y); o[2] = f32_bf16(a.z); o[3] = f32_bf16(a.w);
  o[4] = f32_bf16(b.x); o[5] = f32_bf16(b.y); o[6] = f32_bf16(b.z); o[7] = f32_bf16(b.w);
  *(ushort8*)(dst + i * 8) = o;
}

// gate/up interleave: dst row 2j = gate j, row 2j+1 = up j.  [16384][2048]
__global__ __launch_bounds__(256) void cast_gu_kernel(
    const float* __restrict__ gate, const float* __restrict__ up,
    unsigned short* __restrict__ dst) {
  long i = (long)blockIdx.x * 256 + threadIdx.x;
  long row = i >> 8;
  long col = (i & 255) * 8;
  const float* src = ((row & 1) ? up : gate) + ((row >> 1) << 11) + col;
  const float4 a = *(const float4*)(src);
  const float4 b = *(const float4*)(src + 4);
  ushort8 o;
  o[0] = f32_bf16(a.x); o[1] = f32_bf16(a.y); o[2] = f32_bf16(a.z); o[3] = f32_bf16(a.w);
  o[4] = f32_bf16(b.x); o[5] = f32_bf16(b.y); o[6] = f32_bf16(b.z); o[7] = f32_bf16(b.w);
  *(ushort8*)(dst + i * 8) = o;
}

// ----------------------------------------------------------------- rope ----
__global__ __launch_bounds__(256) void rope_table_kernel(float2* __restrict__ tab) {
  int idx = blockIdx.x * 256 + threadIdx.x;
  int t = idx >> 6, i = idx & 63;
  float inv = __expf(-(float)(2 * i) * (1.0f / 128.0f) * 13.122363377404328f);
  float f = (float)t * inv;
  tab[idx] = make_float2(cosf(f), sinf(f));
}

__global__ __launch_bounds__(256) void rope_apply_kernel(
    unsigned short* __restrict__ qkv, const float2* __restrict__ tab) {
  const int row = blockIdx.x;
  const int tid = threadIdx.x;
#pragma unroll
  for (int it = 0; it < 5; ++it) {
    int p = tid + it * 256;
    int head = p >> 6, i = p & 63;
    int col = (p < 1024) ? (head * 128 + 2 * i) : (2048 + (head - 16) * 128 + 2 * i);
    unsigned short* ptr = qkv + (long)row * 3072 + col;
    float a = bf16_f32(ptr[0]), b = bf16_f32(ptr[1]);
    float2 cs = tab[row * 64 + i];
    float a2 = a * cs.x - b * cs.y;
    float b2 = a * cs.y + b * cs.x;
    ptr[0] = f32_bf16(a2);
    ptr[1] = f32_bf16(b2);
  }
}

// -------------------------------------------------------------- rmsnorm ----
__global__ __launch_bounds__(256) void rmsnorm_kernel(
    const float* __restrict__ x, const float* __restrict__ wgt,
    unsigned short* __restrict__ out) {
  __shared__ float red[4];
  const int row = blockIdx.x;
  const int tid = threadIdx.x;
  const float* xr = x + (long)row * 2048 + tid * 8;
  const float4 v0 = *(const float4*)(xr);
  const float4 v1 = *(const float4*)(xr + 4);
  float ss = v0.x * v0.x + v0.y * v0.y + v0.z * v0.z + v0.w * v0.w +
             v1.x * v1.x + v1.y * v1.y + v1.z * v1.z + v1.w * v1.w;
#pragma unroll
  for (int off = 1; off < 64; off <<= 1) ss += __shfl_xor(ss, off);
  if ((tid & 63) == 0) red[tid >> 6] = ss;
  __syncthreads();
  float tot = red[0] + red[1] + red[2] + red[3];
  float sc = rsqrtf(tot * (1.0f / 2048.0f) + 1e-5f);
  const float4 w0 = *(const float4*)(wgt + tid * 8);
  const float4 w1 = *(const float4*)(wgt + tid * 8 + 4);
  ushort8 o;
  o[0] = f32_bf16(v0.x * sc * w0.x); o[1] = f32_bf16(v0.y * sc * w0.y);
  o[2] = f32_bf16(v0.z * sc * w0.z); o[3] = f32_bf16(v0.w * sc * w0.w);
  o[4] = f32_bf16(v1.x * sc * w1.x); o[5] = f32_bf16(v1.y * sc * w1.y);
  o[6] = f32_bf16(v1.z * sc * w1.z); o[7] = f32_bf16(v1.w * sc * w1.w);
  *(ushort8*)(out + (long)row * 2048 + tid * 8) = o;
}

// --------------------------------------------- BK=32 4-buffer gemm ----
// C[M,N] = A[M,K] @ B[N,K]^T, bf16 in, f32 acc.
// BN=256: 256x256 tile, waves 2Mx4N, per-wave 128x64 (42.7 FLOP/LDS-byte).
// BN=128: 256x128 tile, waves 4Mx2N, per-wave 64x64.
// BK=32, FOUR LDS buffers; prefetch tile t+2 during t; tile-end vmcnt keeps
// t+2's loads in flight. Granule XOR-swizzle: slot = g ^ ((row>>1)&3) --
// read side is a per-thread CONSTANT offset (base rows are multiples of 16);
// write side via inverse-swizzled GLOBAL source, LDS dest stays linear for
// global_load_lds (rule #21). Within each 8-lane b128 service group the
// 16B-slot index (4*(c&1) + g^((c>>1)&3)) is a bijection onto 0..7 ->
// conflict-free. One barrier per K-tile.
// EPI 0: bf16. EPI 1: f32 = res+acc. EPI 2: swiglu.
template <int BN, int EPI>
__global__ __launch_bounds__(512, 2) void gemm_p(
    const unsigned short* __restrict__ A, const unsigned short* __restrict__ B,
    void* __restrict__ Cout, const float* __restrict__ res, int M, int N, int K) {
  constexpr int MH = (BN == 256) ? 2 : 1;   // m-half phases per tile
  constexpr int MF = MH * 4;                 // m-fragments per wave
  constexpr int BL = (BN == 256) ? 2 : 1;    // B loads/thread/tile
  __shared__ __align__(16) unsigned short As[4][256 * 32];
  __shared__ __align__(16) unsigned short Bs[4][BN * 32];

  const int tid = threadIdx.x;
  const int lane = tid & 63;
  const int w = tid >> 6;
  const int c = lane & 15, g = lane >> 4;
  const int wm = (BN == 256) ? (w >> 2) * 128 : (w >> 1) * 64;
  const int wn = (BN == 256) ? (w & 3) * 64 : (w & 1) * 64;
  // per-thread constant swizzled granule offset (elements)
  const int gs = ((g ^ ((c >> 1) & 3)) << 3);

  // bijective XCD swizzle (all grids have nwg % 8 == 0)
  const int id = blockIdx.y * gridDim.x + blockIdx.x;
  const int cpx = (gridDim.x * gridDim.y) >> 3;
  const int sid = (id & 7) * cpx + (id >> 3);
  const int bx = sid % gridDim.x;
  const int by = sid / gridDim.x;
  const long m0 = (long)bx * 256;
  const long n0 = (long)by * BN;

  const f32x4 fzero = {0.f, 0.f, 0.f, 0.f};
  f32x4 acc[MF][4];
#pragma unroll
  for (int i = 0; i < MF; ++i)
#pragma unroll
    for (int j = 0; j < 4; ++j) acc[i][j] = fzero;

  auto stageA = [&](int buf, int k0) {  // 2 loads/thread (1024 granules)
#pragma unroll
    for (int q = 0; q < 2; ++q) {
      int G = q * 512 + tid;
      int sg = (G & 3) ^ ((G >> 3) & 3);  // inverse swizzle on global source
      async16(&As[buf][(q * 512 + (tid & ~63)) * 8],
              A + (m0 + (G >> 2)) * (long)K + k0 + sg * 8);
    }
  };
  auto stageB = [&](int buf, int k0) {
#pragma unroll
    for (int q = 0; q < BL; ++q) {
      int G = q * 512 + tid;
      int sg = (G & 3) ^ ((G >> 3) & 3);
      async16(&Bs[buf][(q * 512 + (tid & ~63)) * 8],
              B + (n0 + (G >> 2)) * (long)K + k0 + sg * 8);
    }
  };

  const int NT = K >> 5;
  stageA(0, 0);
  stageB(0, 0);
  stageA(1, 32);
  stageB(1, 32);
  if constexpr (BN == 256)
    asm volatile("s_waitcnt vmcnt(4)" ::: "memory");
  else
    asm volatile("s_waitcnt vmcnt(3)" ::: "memory");
  __builtin_amdgcn_s_barrier();

  for (int t = 0; t < NT; ++t) {
    const int buf = t & 3;
    const unsigned short* Ab = As[buf];
    const unsigned short* Bb = Bs[buf];
    const bool pf = (t + 2 < NT);
    const int nb = (t + 2) & 3;

    bf16x8 bfr[4];
#pragma unroll
    for (int nf = 0; nf < 4; ++nf)
      bfr[nf] = *(const bf16x8*)(Bb + (wn + nf * 16 + c) * 32 + gs);

#pragma unroll
    for (int mh = 0; mh < MH; ++mh) {
      bf16x8 af[4];
#pragma unroll
      for (int mf = 0; mf < 4; ++mf)
        af[mf] = *(const bf16x8*)(Ab + (wm + mh * 64 + mf * 16 + c) * 32 + gs);
      if (pf) {
        if (mh == 0) stageA(nb, (t + 2) << 5);
        if (mh == MH - 1) stageB(nb, (t + 2) << 5);
      }
      __builtin_amdgcn_sched_barrier(0);
      __builtin_amdgcn_s_setprio(1);
#pragma unroll
      for (int mf = 0; mf < 4; ++mf)
#pragma unroll
        for (int nf = 0; nf < 4; ++nf)
          acc[mh * 4 + mf][nf] = __builtin_amdgcn_mfma_f32_16x16x32_bf16(
              af[mf], bfr[nf], acc[mh * 4 + mf][nf], 0, 0, 0);
      __builtin_amdgcn_s_setprio(0);
    }

    if (pf) {
      if constexpr (BN == 256)
        asm volatile("s_waitcnt vmcnt(4)" ::: "memory");
      else
        asm volatile("s_waitcnt vmcnt(3)" ::: "memory");
    } else {
      asm volatile("s_waitcnt vmcnt(0)" ::: "memory");
    }
    __builtin_amdgcn_s_barrier();
  }

#pragma unroll
  for (int i = 0; i < MF; ++i) {
#pragma unroll
    for (int j = 0; j < 4; ++j) {
      const long row0 = m0 + wm + i * 16 + g * 4;
      const long col = n0 + wn + j * 16 + c;
#pragma unroll
      for (int r = 0; r < 4; ++r) {
        float v = acc[i][j][r];
        if (EPI == 0) {
          ((unsigned short*)Cout)[(row0 + r) * N + col] = f32_bf16(v);
        } else if (EPI == 1) {
          ((float*)Cout)[(row0 + r) * N + col] = res[(row0 + r) * N + col] + v;
        } else {
          float other = __shfl_xor(v, 1);
          if (!(c & 1)) {
            float sg2 = v / (1.0f + __expf(-v));
            ((unsigned short*)Cout)[(row0 + r) * (long)(N >> 1) + (col >> 1)] =
                f32_bf16(sg2 * other);
          }
        }
      }
    }
  }
}

// ----------------------------------------------------------- v transpose ----
__global__ __launch_bounds__(256) void transpose_v(
    const unsigned short* __restrict__ qkv, unsigned short* __restrict__ vT) {
  __shared__ __align__(16) unsigned short tile[64][72];
  const int tx = blockIdx.x;
  const int dx = blockIdx.y;
  const int tid = threadIdx.x;
  const int r = tid >> 3, cg = tid & 7;
#pragma unroll
  for (int it = 0; it < 2; ++it) {
    const unsigned short* src =
        qkv + (long)(tx * 64 + r + it * 32) * 3072 + 2560 + dx * 64 + cg * 8;
    *(ushort8*)(&tile[r + it * 32][cg * 8]) = *(const ushort8*)src;
  }
  __syncthreads();
#pragma unroll
  for (int it = 0; it < 2; ++it) {
    int d = r + it * 32;
    ushort8 v;
#pragma unroll
    for (int j = 0; j < 8; ++j) v[j] = tile[cg * 8 + j][d];
    *(ushort8*)(vT + (long)(dx * 64 + d) * 4096 + tx * 64 + cg * 8) = v;
  }
}

// ------------------------------------------------------------- attention ----
// Swapped-operand causal GQA flash attention (see round-1 notes).
__global__ __launch_bounds__(512, 2) void attn_kernel(
    const unsigned short* __restrict__ qkv, const unsigned short* __restrict__ vT,
    unsigned short* __restrict__ y) {
  constexpr float SCL = 0.08838834764831845f * 1.4426950408889634f;
  __shared__ __align__(16) unsigned short Kb[2][64 * 128];
  __shared__ __align__(16) unsigned short Vb[2][128 * 64];

  const int tid = threadIdx.x;
  const int lane = tid & 63;
  const int w = tid >> 6;
  const int c = lane & 15, g = lane >> 4;
  const int h = blockIdx.x >> 4;
  const int pid = blockIdx.x & 15;
  const int kvh = h >> 2;
  const int qt = (w < 4) ? pid : (31 - pid);
  const int q0w = qt * 128 + (w & 3) * 32;
  const int nsteps = 2 * (31 - pid) + 2;

  const f32x4 fzero = {0.f, 0.f, 0.f, 0.f};

  bf16x8 qf[2][4];
#pragma unroll
  for (int mt = 0; mt < 2; ++mt)
#pragma unroll
    for (int kk = 0; kk < 4; ++kk)
      qf[mt][kk] = *(const bf16x8*)(qkv + (long)(q0w + mt * 16 + c) * 3072 +
                                    h * 128 + kk * 32 + g * 8);

  f32x4 o[2][8];
#pragma unroll
  for (int mt = 0; mt < 2; ++mt)
#pragma unroll
    for (int dt = 0; dt < 8; ++dt) o[mt][dt] = fzero;
  float m[2] = {-1e30f, -1e30f}, l[2] = {0.f, 0.f};

  auto stage = [&](int buf, int kv0) {
#pragma unroll
    for (int k = 0; k < 2; ++k) {
      int G = k * 512 + tid;
      int row = G >> 4, colg = (G & 15) ^ (row & 7);
      async16(&Kb[buf][(k * 512 + (tid & ~63)) * 8],
              qkv + (long)(kv0 + row) * 3072 + 2048 + kvh * 128 + colg * 8);
    }
#pragma unroll
    for (int k = 0; k < 2; ++k) {
      int G = k * 512 + tid;
      int row = G >> 3, colg = (G & 7) ^ (row & 7);
      async16(&Vb[buf][(k * 512 + (tid & ~63)) * 8],
              vT + (long)(kvh * 128 + row) * 4096 + kv0 + colg * 8);
    }
  };

  stage(0, 0);
  for (int s = 0; s < nsteps; ++s) {
    const int kv0 = s * 64;
    const int bi = s & 1;
    if (s + 1 < nsteps) {
      stage(bi ^ 1, kv0 + 64);
      asm volatile("s_waitcnt vmcnt(4)" ::: "memory");
    } else {
      asm volatile("s_waitcnt vmcnt(0)" ::: "memory");
    }
    __builtin_amdgcn_s_barrier();
    if (kv0 <= q0w + 31) {
      const unsigned short* Ks = Kb[bi];
      const unsigned short* Vs = Vb[bi];
      f32x4 sv[2][4];
#pragma unroll
      for (int mt = 0; mt < 2; ++mt)
#pragma unroll
        for (int nt = 0; nt < 4; ++nt) sv[mt][nt] = fzero;
#pragma unroll
      for (int kk = 0; kk < 4; ++kk) {
        bf16x8 kf[4];
#pragma unroll
        for (int nt = 0; nt < 4; ++nt)
          kf[nt] = *(const bf16x8*)(Ks + (nt * 16 + c) * 128 +
                                    (((kk * 4 + g) ^ (c & 7)) << 3));
#pragma unroll
        for (int mt = 0; mt < 2; ++mt)
#pragma unroll
          for (int nt = 0; nt < 4; ++nt)
            sv[mt][nt] = __builtin_amdgcn_mfma_f32_16x16x32_bf16(
                kf[nt], qf[mt][kk], sv[mt][nt], 0, 0, 0);
      }
      const bool need_mask = (kv0 + 63 > q0w);
      float al[2];
#pragma unroll
      for (int mt = 0; mt < 2; ++mt) {
        const int qrow = q0w + mt * 16 + c;
#pragma unroll
        for (int nt = 0; nt < 4; ++nt)
#pragma unroll
          for (int r = 0; r < 4; ++r) {
            float xx = sv[mt][nt][r] * SCL;
            if (need_mask && (kv0 + nt * 16 + g * 4 + r > qrow)) xx = -3.0e38f;
            sv[mt][nt][r] = xx;
          }
        float mx = -3.0e38f;
#pragma unroll
        for (int nt = 0; nt < 4; ++nt)
#pragma unroll
          for (int r = 0; r < 4; ++r) mx = fmaxf(mx, sv[mt][nt][r]);
        mx = fmaxf(mx, __shfl_xor(mx, 16));
        mx = fmaxf(mx, __shfl_xor(mx, 32));
        const float mn = fmaxf(m[mt], mx);
        const float a = exp2f(m[mt] - mn);
        m[mt] = mn;
        al[mt] = a;
        float rs = 0.f;
#pragma unroll
        for (int nt = 0; nt < 4; ++nt)
#pragma unroll
          for (int r = 0; r < 4; ++r) {
            float p = exp2f(sv[mt][nt][r] - mn);
            sv[mt][nt][r] = p;
            rs += p;
          }
        rs += __shfl_xor(rs, 16);
        rs += __shfl_xor(rs, 32);
        l[mt] = l[mt] * a + rs;
#pragma unroll
        for (int dt = 0; dt < 8; ++dt) o[mt][dt] *= al[mt];
      }
#pragma unroll
      for (int nt = 0; nt < 4; ++nt) {
        bf16x4 pb[2];
#pragma unroll
        for (int mt = 0; mt < 2; ++mt) {
          int lo_, hi_;
          float s0 = sv[mt][nt][0], s1 = sv[mt][nt][1];
          float s2 = sv[mt][nt][2], s3 = sv[mt][nt][3];
          asm("v_cvt_pk_bf16_f32 %0, %1, %2" : "=v"(lo_) : "v"(s0), "v"(s1));
          asm("v_cvt_pk_bf16_f32 %0, %1, %2" : "=v"(hi_) : "v"(s2), "v"(s3));
          int2 pk = make_int2(lo_, hi_);
          pb[mt] = __builtin_bit_cast(bf16x4, pk);
        }
#pragma unroll
        for (int dt = 0; dt < 8; ++dt) {
          bf16x4 vt = *(const bf16x4*)(Vs + (dt * 16 + c) * 64 +
                                       (((nt * 2 + (g >> 1)) ^ (c & 7)) << 3) +
                                       (g & 1) * 4);
          o[0][dt] = mfma16(vt, pb[0], o[0][dt]);
          o[1][dt] = mfma16(vt, pb[1], o[1][dt]);
        }
      }
    }
    __builtin_amdgcn_s_barrier();
  }
#pragma unroll
  for (int mt = 0; mt < 2; ++mt) {
    const float inv = 1.0f / l[mt];
    const long qrow = q0w + mt * 16 + c;
#pragma unroll
    for (int dt = 0; dt < 8; ++dt) {
      us4 st;
      st[0] = f32_bf16(o[mt][dt][0] * inv);
      st[1] = f32_bf16(o[mt][dt][1] * inv);
      st[2] = f32_bf16(o[mt][dt][2] * inv);
      st[3] = f32_bf16(o[mt][dt][3] * inv);
      *(us4*)(y + qrow * 2048 + h * 128 + dt * 16 + g * 4) = st;
    }
  }
}

// ------------------------------------------------------------------ host ----
extern "C" void kernel_launch(void* const* d_in, const int* in_sizes, int n_in,
                              void* d_out, int out_size, void* d_ws, size_t ws_size,
                              hipStream_t stream) {
  (void)in_sizes; (void)n_in; (void)out_size; (void)ws_size;
  const float* x      = (const float*)d_in[0];
  const float* attn_w = (const float*)d_in[2];
  const float* wq     = (const float*)d_in[3];
  const float* wk     = (const float*)d_in[4];
  const float* wv     = (const float*)d_in[5];
  const float* wo     = (const float*)d_in[6];
  const float* ffn_w  = (const float*)d_in[7];
  const float* wg     = (const float*)d_in[8];
  const float* wu     = (const float*)d_in[9];
  const float* wd     = (const float*)d_in[10];
  float* out = (float*)d_out;

  char* ws = (char*)d_ws;
  size_t off = 0;
  auto alloc = [&](size_t bytes) {
    char* p = ws + off;
    off += (bytes + 255) & ~(size_t)255;
    return p;
  };
  float2* rope_tab        = (float2*)alloc(4096UL * 64 * sizeof(float2));
  unsigned short* wqkv_b  = (unsigned short*)alloc(3072UL * 2048 * 2);
  unsigned short* wo_b    = (unsigned short*)alloc(2048UL * 2048 * 2);
  unsigned short* wgu_b   = (unsigned short*)alloc(16384UL * 2048 * 2);
  unsigned short* wd_b    = (unsigned short*)alloc(2048UL * 8192 * 2);
  unsigned short* h_b     = (unsigned short*)alloc(4096UL * 2048 * 2);
  unsigned short* qkv_b   = (unsigned short*)alloc(4096UL * 3072 * 2);
  unsigned short* vT_b    = (unsigned short*)alloc(512UL * 4096 * 2);
  unsigned short* y_b     = (unsigned short*)alloc(4096UL * 2048 * 2);
  float* r1               = (float*)alloc(4096UL * 2048 * 4);
  unsigned short* t_b     = (unsigned short*)alloc(4096UL * 8192 * 2);

  // weight casts
  cast_bf16_kernel<<<2048, 256, 0, stream>>>(wq, wqkv_b, 524288);
  cast_bf16_kernel<<<512, 256, 0, stream>>>(wk, wqkv_b + 2048L * 2048, 131072);
  cast_bf16_kernel<<<512, 256, 0, stream>>>(wv, wqkv_b + 2560L * 2048, 131072);
  cast_bf16_kernel<<<2048, 256, 0, stream>>>(wo, wo_b, 524288);
  cast_gu_kernel<<<16384, 256, 0, stream>>>(wg, wu, wgu_b);
  cast_bf16_kernel<<<8192, 256, 0, stream>>>(wd, wd_b, 2097152);
  rope_table_kernel<<<1024, 256, 0, stream>>>(rope_tab);

  // attn branch
  rmsnorm_kernel<<<4096, 256, 0, stream>>>(x, attn_w, h_b);
  {
    dim3 grid(16, 12);
    gemm_p<256, 0><<<grid, 512, 0, stream>>>(h_b, wqkv_b, qkv_b, nullptr, 4096, 3072, 2048);
  }
  rope_apply_kernel<<<4096, 256, 0, stream>>>(qkv_b, rope_tab);
  {
    dim3 grid(64, 8);
    transpose_v<<<grid, 256, 0, stream>>>(qkv_b, vT_b);
  }
  attn_kernel<<<256, 512, 0, stream>>>(qkv_b, vT_b, y_b);
  {
    dim3 grid(16, 16);
    gemm_p<128, 1><<<grid, 512, 0, stream>>>(y_b, wo_b, r1, x, 4096, 2048, 2048);
  }

  // ffn branch
  rmsnorm_kernel<<<4096, 256, 0, stream>>>(r1, ffn_w, h_b);
  {
    dim3 grid(16, 64);
    gemm_p<256, 2><<<grid, 512, 0, stream>>>(h_b, wgu_b, t_b, nullptr, 4096, 16384, 2048);
  }
  {
    dim3 grid(16, 16);
    gemm_p<128, 1><<<grid, 512, 0, stream>>>(t_b, wd_b, out, r1, 4096, 2048, 8192);
  }
}